// Round 2
// baseline (69504.620 us; speedup 1.0000x reference)
//
#include <hip/hip_runtime.h>
#include <hip/hip_bf16.h>
#include <cstdint>
#include <cstddef>

// Problem constants
#define L_SEQ   4096
#define BATCH_N 16
#define BLTOK   (BATCH_N * L_SEQ)   // 65536 tokens
#define DMODEL  128
#define DINNER  256
#define DSTATE  32
#define DTRANK  8

// ---------------------------------------------------------------------------
// Pre-conv (1->128 channels, k=7, same padding) + exact GELU
// ---------------------------------------------------------------------------
__global__ __launch_bounds__(128) void pre_conv_gelu(
    const float* __restrict__ x,      // (16,4096,1)
    const float* __restrict__ w,      // (128,1,7)
    const float* __restrict__ bias,   // (128,)
    float* __restrict__ h)            // (BLTOK,128)
{
    int r = blockIdx.x;
    int c = threadIdx.x;
    int b = r >> 12;
    int l = r & 4095;
    float acc = bias[c];
    const float* wp = w + c * 7;
#pragma unroll
    for (int k = 0; k < 7; ++k) {
        int ll = l + k - 3;
        if (ll >= 0 && ll < L_SEQ)
            acc += x[(size_t)(b << 12) + ll] * wp[k];
    }
    float ge = 0.5f * acc * (1.f + erff(acc * 0.70710678118654752f));
    h[(size_t)r * DMODEL + c] = ge;
}

// ---------------------------------------------------------------------------
// Tiled fp32 GEMM: acc[M,N] = A[M,K] @ W[N,K]^T
// 64x64 tile, 256 threads, 4x4 accum per thread, K-step 16.
// rev!=0: read A rows per-batch flipped (L=4096).
// Epilogue modes:
//   0: Out[row*ldc+col] = acc            (col<N guarded)       [x_proj]
//   1: col<256 -> Out[row*256+col]=acc ; col>=256 -> Zb bf16   [in_proj]
//   2: Out[row*128+col] = acc                                  [out_proj fwd]
//   3: Out[flip(row)*128+col] = 0.5*(existing + acc)           [out_proj bwd]
// ---------------------------------------------------------------------------
__global__ __launch_bounds__(256) void gemm_rk(
    const float* __restrict__ In, int lda,
    const float* __restrict__ W,      // N x K row-major
    float* __restrict__ Out, int ldc,
    __hip_bfloat16* __restrict__ Zb,
    int N, int K, int rev, int mode)
{
    __shared__ float As[16][64];
    __shared__ float Bs[16][64];

    int tid = threadIdx.x;
    int tx = tid & 15;
    int ty = tid >> 4;
    int mr = blockIdx.y * 64;
    int nc = blockIdx.x * 64;

    int lrow = tid >> 2;          // 0..63
    int kq   = (tid & 3) * 4;     // 0,4,8,12

    int gr = mr + lrow;
    if (rev) {
        int b = gr >> 12;
        int l = gr & 4095;
        gr = (b << 12) + (4095 - l);
    }
    const float* Arow = In + (size_t)gr * lda;
    int wn = nc + lrow;
    bool wvalid = (wn < N);
    const float* Wrow = W + (size_t)wn * K;

    float acc[4][4] = {};

    for (int k0 = 0; k0 < K; k0 += 16) {
        float4 av = *(const float4*)(Arow + k0 + kq);
        float4 bv = wvalid ? *(const float4*)(Wrow + k0 + kq)
                           : make_float4(0.f, 0.f, 0.f, 0.f);
        __syncthreads();
        As[kq + 0][lrow] = av.x; As[kq + 1][lrow] = av.y;
        As[kq + 2][lrow] = av.z; As[kq + 3][lrow] = av.w;
        Bs[kq + 0][lrow] = bv.x; Bs[kq + 1][lrow] = bv.y;
        Bs[kq + 2][lrow] = bv.z; Bs[kq + 3][lrow] = bv.w;
        __syncthreads();
#pragma unroll
        for (int k = 0; k < 16; ++k) {
            float4 a = *(const float4*)&As[k][ty * 4];
            float4 b = *(const float4*)&Bs[k][tx * 4];
            acc[0][0] += a.x * b.x; acc[0][1] += a.x * b.y;
            acc[0][2] += a.x * b.z; acc[0][3] += a.x * b.w;
            acc[1][0] += a.y * b.x; acc[1][1] += a.y * b.y;
            acc[1][2] += a.y * b.z; acc[1][3] += a.y * b.w;
            acc[2][0] += a.z * b.x; acc[2][1] += a.z * b.y;
            acc[2][2] += a.z * b.z; acc[2][3] += a.z * b.w;
            acc[3][0] += a.w * b.x; acc[3][1] += a.w * b.y;
            acc[3][2] += a.w * b.z; acc[3][3] += a.w * b.w;
        }
    }

#pragma unroll
    for (int i = 0; i < 4; ++i) {
        int row = mr + ty * 4 + i;
#pragma unroll
        for (int j = 0; j < 4; ++j) {
            int col = nc + tx * 4 + j;
            float v = acc[i][j];
            if (mode == 0) {
                if (col < N) Out[(size_t)row * ldc + col] = v;
            } else if (mode == 1) {
                if (col < 256) Out[(size_t)row * 256 + col] = v;
                else           Zb[(size_t)row * 256 + (col - 256)] = __float2bfloat16(v);
            } else if (mode == 2) {
                Out[(size_t)row * 128 + col] = v;
            } else {
                int b = row >> 12, l = row & 4095;
                size_t o = ((size_t)(b << 12) + (4095 - l)) * 128 + col;
                Out[o] = 0.5f * (Out[o] + v);
            }
        }
    }
}

// ---------------------------------------------------------------------------
// Depthwise causal conv (k=8, pad (7,0)) + SiLU.  u (stride 256) -> uc
// ---------------------------------------------------------------------------
__global__ __launch_bounds__(256) void dwconv_silu(
    const float* __restrict__ u,      // (BLTOK,256)
    const float* __restrict__ cw,     // (256,1,8)
    const float* __restrict__ cb,     // (256,)
    float* __restrict__ uc)           // (BLTOK,256)
{
    int r = blockIdx.x;
    int d = threadIdx.x;
    int b = r >> 12;
    int l = r & 4095;
    float acc = cb[d];
    const float* wp = cw + d * 8;
#pragma unroll
    for (int k = 0; k < 8; ++k) {
        int ll = l - 7 + k;
        if (ll >= 0)
            acc += u[((size_t)(b << 12) + ll) * DINNER + d] * wp[k];
    }
    float s = acc / (1.f + expf(-acc));
    uc[(size_t)r * DINNER + d] = s;
}

// ---------------------------------------------------------------------------
// Selective scan, fused: dt-proj + softplus, recurrence, C-reduce, D skip,
// silu(z) gate.  One (b,d) per 32-lane half-wave; lane = state n.
// y overwrites uc in place (row t read before written).
// ---------------------------------------------------------------------------
__global__ __launch_bounds__(256) void scan_kernel(
    const float* __restrict__ dbc,    // (BLTOK,72) compact
    float* __restrict__ ucy,          // (BLTOK,256): uc in, y out (in-place)
    const __hip_bfloat16* __restrict__ zb, // (BLTOK,256)
    const float* __restrict__ dt_w,   // (256,8)
    const float* __restrict__ dt_b,   // (256,)
    const float* __restrict__ a_log,  // (256,32)
    const float* __restrict__ Dp)     // (256,)
{
    int tid  = threadIdx.x;
    int half = (blockIdx.x * blockDim.x + tid) >> 5;  // 0..4095
    int n    = tid & 31;
    int b    = half >> 8;
    int d    = half & 255;

    float a = -expf(a_log[d * DSTATE + n]);
    const float* wrow = dt_w + d * DTRANK;
    float w0 = wrow[0], w1 = wrow[1], w2 = wrow[2], w3 = wrow[3];
    float w4 = wrow[4], w5 = wrow[5], w6 = wrow[6], w7 = wrow[7];
    float bias = dt_b[d];
    float Dd = Dp[d];

    float hst = 0.f;
    size_t base = (size_t)b * L_SEQ;

    for (int t = 0; t < L_SEQ; ++t) {
        const float* row = dbc + (base + t) * 72;
        float dtr = bias + row[0] * w0 + row[1] * w1 + row[2] * w2 + row[3] * w3
                         + row[4] * w4 + row[5] * w5 + row[6] * w6 + row[7] * w7;
        float dt = (dtr > 20.f) ? dtr : log1pf(expf(dtr));
        float ut = ucy[(base + t) * DINNER + d];
        float Bn = row[8 + n];
        float Cn = row[40 + n];

        hst = hst * expf(dt * a) + (dt * ut) * Bn;

        float p = hst * Cn;
        p += __shfl_xor(p, 16);
        p += __shfl_xor(p, 8);
        p += __shfl_xor(p, 4);
        p += __shfl_xor(p, 2);
        p += __shfl_xor(p, 1);

        if (n == 0) {
            float zt = __bfloat162float(zb[(base + t) * DINNER + d]);
            float yv = p + ut * Dd;
            float sig = 1.f / (1.f + expf(-zt));
            ucy[(base + t) * DINNER + d] = yv * (zt * sig);
        }
    }
}

// ---------------------------------------------------------------------------
// h = LayerNorm(osum + h)   (osum already holds 0.5*(f + flip(b)))
// ---------------------------------------------------------------------------
__global__ __launch_bounds__(128) void combine_ln(
    const float* __restrict__ osum,   // (BLTOK,128)
    float* __restrict__ h,            // (BLTOK,128)
    const float* __restrict__ g,
    const float* __restrict__ be)
{
    __shared__ float red[128];
    int r = blockIdx.x;
    int c = threadIdx.x;
    size_t idx = (size_t)r * DMODEL + c;

    float v = osum[idx] + h[idx];

    red[c] = v;
    __syncthreads();
    for (int s = 64; s > 0; s >>= 1) {
        if (c < s) red[c] += red[c + s];
        __syncthreads();
    }
    float mu = red[0] * (1.f / 128.f);
    __syncthreads();
    float dv = v - mu;
    red[c] = dv * dv;
    __syncthreads();
    for (int s = 64; s > 0; s >>= 1) {
        if (c < s) red[c] += red[c + s];
        __syncthreads();
    }
    float var = red[0] * (1.f / 128.f);
    h[idx] = dv * rsqrtf(var + 1e-5f) * g[c] + be[c];
}

// ---------------------------------------------------------------------------
__global__ __launch_bounds__(128) void final_proj(
    const float* __restrict__ h,
    const float* __restrict__ pw,     // (1,128)
    const float* __restrict__ pb,     // (1,)
    float* __restrict__ out)          // (BLTOK,)
{
    __shared__ float red[128];
    int r = blockIdx.x;
    int c = threadIdx.x;
    red[c] = h[(size_t)r * DMODEL + c] * pw[c];
    __syncthreads();
    for (int s = 64; s > 0; s >>= 1) {
        if (c < s) red[c] += red[c + s];
        __syncthreads();
    }
    if (c == 0) out[r] = red[0] + pb[0];
}

// ---------------------------------------------------------------------------
extern "C" void kernel_launch(void* const* d_in, const int* in_sizes, int n_in,
                              void* d_out, int out_size, void* d_ws, size_t ws_size,
                              hipStream_t stream)
{
    const float* x    = (const float*)d_in[0];
    const float* pcw  = (const float*)d_in[1];
    const float* pcb  = (const float*)d_in[2];
    const float* inw  = (const float*)d_in[3];
    const float* cw   = (const float*)d_in[4];
    const float* cb   = (const float*)d_in[5];
    const float* xpw  = (const float*)d_in[6];
    const float* dtw  = (const float*)d_in[7];
    const float* dtb  = (const float*)d_in[8];
    const float* alog = (const float*)d_in[9];
    const float* dpar = (const float*)d_in[10];
    const float* outw = (const float*)d_in[11];
    const float* lng  = (const float*)d_in[12];
    const float* lnb  = (const float*)d_in[13];
    const float* pw   = (const float*)d_in[14];
    const float* pb   = (const float*)d_in[15];
    float* out = (float*)d_out;

    // Workspace layout — 224 MiB total (lifetime-aliased):
    //   h   : BLTOK*128 f32   persistent residual stream
    //   A   : BLTOK*256 f32   u (in_proj) -> dead after dwconv -> dbc (72 compact)
    //   zb  : BLTOK*256 bf16  z gate
    //   C   : BLTOK*256 f32   uc (dwconv) -> y (scan, in-place)
    //   E   : BLTOK*128 f32   0.5*(fwd + flip(bwd)) out accumulation
    float* h  = (float*)d_ws;
    float* A  = h + (size_t)BLTOK * 128;
    __hip_bfloat16* zb = (__hip_bfloat16*)(A + (size_t)BLTOK * 256);
    float* C  = (float*)(zb + (size_t)BLTOK * 256);
    float* E  = C + (size_t)BLTOK * 256;

    pre_conv_gelu<<<BLTOK, 128, 0, stream>>>(x, pcw, pcb, h);

    for (int blk = 0; blk < 6; ++blk) {
        for (int dir = 0; dir < 2; ++dir) {
            int s = blk * 2 + dir;
            // in_proj: u -> A, z -> zb (bf16).  N=512, K=128
            gemm_rk<<<dim3(8, BLTOK / 64), 256, 0, stream>>>(
                h, DMODEL, inw + (size_t)s * 512 * 128, A, 0, zb,
                512, 128, dir, 1);
            // depthwise causal conv + silu: A -> C
            dwconv_silu<<<BLTOK, 256, 0, stream>>>(
                A, cw + (size_t)s * 256 * 8, cb + (size_t)s * 256, C);
            // x_proj: dbc = C @ xp_w^T -> A (compact ldc=72).  N=72, K=256
            gemm_rk<<<dim3(2, BLTOK / 64), 256, 0, stream>>>(
                C, DINNER, xpw + (size_t)s * 72 * 256, A, 72, nullptr,
                72, 256, 0, 0);
            // fused dt + scan + gate: y overwrites C
            scan_kernel<<<512, 256, 0, stream>>>(
                A, C, zb,
                dtw + (size_t)s * 256 * 8, dtb + (size_t)s * 256,
                alog + (size_t)s * 256 * 32, dpar + (size_t)s * 256);
            // out_proj: E = y @ out_w^T (fwd) / flip-accumulate (bwd).  N=128, K=256
            gemm_rk<<<dim3(2, BLTOK / 64), 256, 0, stream>>>(
                C, DINNER, outw + (size_t)s * 128 * 256, E, 0, nullptr,
                128, 256, 0, 2 + dir);
        }
        combine_ln<<<BLTOK, 128, 0, stream>>>(
            E, h, lng + blk * 128, lnb + blk * 128);
    }

    final_proj<<<BLTOK, 128, 0, stream>>>(h, pw, pb, out);
}

// Round 3
// 21310.339 us; speedup vs baseline: 3.2615x; 3.2615x over previous
//
#include <hip/hip_runtime.h>
#include <hip/hip_bf16.h>
#include <cstdint>
#include <cstddef>

// Problem constants
#define L_SEQ   4096
#define BATCH_N 16
#define BLTOK   (BATCH_N * L_SEQ)   // 65536 tokens
#define DMODEL  128
#define DINNER  256
#define DSTATE  32
#define DTRANK  8

// Scan chunking
#define LC  128                     // chunk length
#define GCH 32                      // chunks per sequence (LC*GCH == L_SEQ)

// ---------------------------------------------------------------------------
// Pre-conv (1->128 channels, k=7, same padding) + exact GELU
// ---------------------------------------------------------------------------
__global__ __launch_bounds__(128) void pre_conv_gelu(
    const float* __restrict__ x,      // (16,4096,1)
    const float* __restrict__ w,      // (128,1,7)
    const float* __restrict__ bias,   // (128,)
    float* __restrict__ h)            // (BLTOK,128)
{
    int r = blockIdx.x;
    int c = threadIdx.x;
    int b = r >> 12;
    int l = r & 4095;
    float acc = bias[c];
    const float* wp = w + c * 7;
#pragma unroll
    for (int k = 0; k < 7; ++k) {
        int ll = l + k - 3;
        if (ll >= 0 && ll < L_SEQ)
            acc += x[(size_t)(b << 12) + ll] * wp[k];
    }
    float ge = 0.5f * acc * (1.f + erff(acc * 0.70710678118654752f));
    h[(size_t)r * DMODEL + c] = ge;
}

// ---------------------------------------------------------------------------
// Tiled fp32 GEMM: acc[M,N] = A[M,K] @ W[N,K]^T
// 64x64 tile, 256 threads, 4x4 accum per thread, K-step 16.
// rev!=0: read A rows per-batch flipped (L=4096).
// Epilogue modes:
//   0: Out[row*ldc+col] = acc            (col<N guarded)       [x_proj]
//   1: col<256 -> Out[row*256+col]=acc ; col>=256 -> Zb bf16   [in_proj]
//   2: Out[row*128+col] = acc                                  [out_proj fwd]
//   3: Out[flip(row)*128+col] = 0.5*(existing + acc)           [out_proj bwd]
// ---------------------------------------------------------------------------
__global__ __launch_bounds__(256) void gemm_rk(
    const float* __restrict__ In, int lda,
    const float* __restrict__ W,      // N x K row-major
    float* __restrict__ Out, int ldc,
    __hip_bfloat16* __restrict__ Zb,
    int N, int K, int rev, int mode)
{
    __shared__ float As[16][64];
    __shared__ float Bs[16][64];

    int tid = threadIdx.x;
    int tx = tid & 15;
    int ty = tid >> 4;
    int mr = blockIdx.y * 64;
    int nc = blockIdx.x * 64;

    int lrow = tid >> 2;          // 0..63
    int kq   = (tid & 3) * 4;     // 0,4,8,12

    int gr = mr + lrow;
    if (rev) {
        int b = gr >> 12;
        int l = gr & 4095;
        gr = (b << 12) + (4095 - l);
    }
    const float* Arow = In + (size_t)gr * lda;
    int wn = nc + lrow;
    bool wvalid = (wn < N);
    const float* Wrow = W + (size_t)wn * K;

    float acc[4][4] = {};

    for (int k0 = 0; k0 < K; k0 += 16) {
        float4 av = *(const float4*)(Arow + k0 + kq);
        float4 bv = wvalid ? *(const float4*)(Wrow + k0 + kq)
                           : make_float4(0.f, 0.f, 0.f, 0.f);
        __syncthreads();
        As[kq + 0][lrow] = av.x; As[kq + 1][lrow] = av.y;
        As[kq + 2][lrow] = av.z; As[kq + 3][lrow] = av.w;
        Bs[kq + 0][lrow] = bv.x; Bs[kq + 1][lrow] = bv.y;
        Bs[kq + 2][lrow] = bv.z; Bs[kq + 3][lrow] = bv.w;
        __syncthreads();
#pragma unroll
        for (int k = 0; k < 16; ++k) {
            float4 a = *(const float4*)&As[k][ty * 4];
            float4 b = *(const float4*)&Bs[k][tx * 4];
            acc[0][0] += a.x * b.x; acc[0][1] += a.x * b.y;
            acc[0][2] += a.x * b.z; acc[0][3] += a.x * b.w;
            acc[1][0] += a.y * b.x; acc[1][1] += a.y * b.y;
            acc[1][2] += a.y * b.z; acc[1][3] += a.y * b.w;
            acc[2][0] += a.z * b.x; acc[2][1] += a.z * b.y;
            acc[2][2] += a.z * b.z; acc[2][3] += a.z * b.w;
            acc[3][0] += a.w * b.x; acc[3][1] += a.w * b.y;
            acc[3][2] += a.w * b.z; acc[3][3] += a.w * b.w;
        }
    }

#pragma unroll
    for (int i = 0; i < 4; ++i) {
        int row = mr + ty * 4 + i;
#pragma unroll
        for (int j = 0; j < 4; ++j) {
            int col = nc + tx * 4 + j;
            float v = acc[i][j];
            if (mode == 0) {
                if (col < N) Out[(size_t)row * ldc + col] = v;
            } else if (mode == 1) {
                if (col < 256) Out[(size_t)row * 256 + col] = v;
                else           Zb[(size_t)row * 256 + (col - 256)] = __float2bfloat16(v);
            } else if (mode == 2) {
                Out[(size_t)row * 128 + col] = v;
            } else {
                int b = row >> 12, l = row & 4095;
                size_t o = ((size_t)(b << 12) + (4095 - l)) * 128 + col;
                Out[o] = 0.5f * (Out[o] + v);
            }
        }
    }
}

// ---------------------------------------------------------------------------
// Depthwise causal conv (k=8, pad (7,0)) + SiLU.  u (stride 256) -> uc
// ---------------------------------------------------------------------------
__global__ __launch_bounds__(256) void dwconv_silu(
    const float* __restrict__ u,      // (BLTOK,256)
    const float* __restrict__ cw,     // (256,1,8)
    const float* __restrict__ cb,     // (256,)
    float* __restrict__ uc)           // (BLTOK,256)
{
    int r = blockIdx.x;
    int d = threadIdx.x;
    int b = r >> 12;
    int l = r & 4095;
    float acc = cb[d];
    const float* wp = cw + d * 8;
#pragma unroll
    for (int k = 0; k < 8; ++k) {
        int ll = l - 7 + k;
        if (ll >= 0)
            acc += u[((size_t)(b << 12) + ll) * DINNER + d] * wp[k];
    }
    float s = acc / (1.f + expf(-acc));
    uc[(size_t)r * DINNER + d] = s;
}

// ---------------------------------------------------------------------------
// Chunked selective scan, phase 1: per-chunk zero-init local scan.
// One (b,d,g) per 32-lane half-wave, lane = state n.
// Lane-distributed dt: lane j computes dt/du for timestep t0+j, broadcast
// via __shfl in the inner loop.
// Stores chunk aggregates: agg[(bd*GCH+g)*64 + n]     = P  (decay product)
//                          agg[(bd*GCH+g)*64 + 32 + n] = h_end (zero-init)
// ---------------------------------------------------------------------------
__global__ __launch_bounds__(256) void scan_phase1(
    const float* __restrict__ dbc,    // (BLTOK,72) compact
    const float* __restrict__ u,      // (BLTOK,256)
    float* __restrict__ agg,          // (4096, GCH, 64)
    const float* __restrict__ dt_w,   // (256,8)
    const float* __restrict__ dt_b,   // (256,)
    const float* __restrict__ a_log)  // (256,32)
{
    int tid = threadIdx.x;
    int hw  = (blockIdx.x << 3) + (tid >> 5);   // global half-wave id
    int n   = tid & 31;
    int g   = hw & (GCH - 1);
    int bd  = hw >> 5;
    int d   = bd & 255;
    int b   = bd >> 8;

    float a = -expf(a_log[d * DSTATE + n]);
    const float* wr = dt_w + d * DTRANK;
    float w0 = wr[0], w1 = wr[1], w2 = wr[2], w3 = wr[3];
    float w4 = wr[4], w5 = wr[5], w6 = wr[6], w7 = wr[7];
    float bias = dt_b[d];

    size_t base = (size_t)b * L_SEQ + (size_t)g * LC;
    float P = 1.f, hst = 0.f;

    for (int t0 = 0; t0 < LC; t0 += 32) {
        size_t myt = base + t0 + n;
        const float* row = dbc + myt * 72;
        float4 r0 = *(const float4*)row;
        float4 r1 = *(const float4*)(row + 4);
        float dtr = bias + r0.x * w0 + r0.y * w1 + r0.z * w2 + r0.w * w3
                         + r1.x * w4 + r1.y * w5 + r1.z * w6 + r1.w * w7;
        float dtv = (dtr > 15.f) ? dtr : __logf(1.f + __expf(dtr));
        float du  = dtv * u[myt * DINNER + d];
        const float* rb = dbc + (base + t0) * 72 + 8 + n;
#pragma unroll
        for (int j = 0; j < 32; ++j) {
            float dt_j = __shfl(dtv, j, 32);
            float du_j = __shfl(du,  j, 32);
            float Bn = rb[j * 72];
            float dA = __expf(dt_j * a);
            P   *= dA;
            hst  = hst * dA + du_j * Bn;
        }
    }
    size_t o = ((size_t)bd * GCH + g) * 64;
    agg[o + n]      = P;
    agg[o + 32 + n] = hst;
}

// ---------------------------------------------------------------------------
// Phase 2: exact serial combine over the GCH chunk aggregates.
// Overwrites the h_end slot with the chunk's incoming state h_in.
// ---------------------------------------------------------------------------
__global__ __launch_bounds__(256) void scan_phase2(float* __restrict__ agg)
{
    int tid = threadIdx.x;
    int bd  = (blockIdx.x << 3) + (tid >> 5);   // 0..4095
    int n   = tid & 31;

    float hrun = 0.f;
    for (int g = 0; g < GCH; ++g) {
        size_t o = ((size_t)bd * GCH + g) * 64;
        float Pg = agg[o + n];
        float he = agg[o + 32 + n];
        agg[o + 32 + n] = hrun;          // h_in for chunk g
        hrun = hrun * Pg + he;
    }
}

// ---------------------------------------------------------------------------
// Phase 3: rerun local scan seeded with h_in; fused y = <h,C> reduction,
// D skip and silu(z) gate.  y overwrites uc in place.
// ---------------------------------------------------------------------------
__global__ __launch_bounds__(256) void scan_phase3(
    const float* __restrict__ dbc,    // (BLTOK,72)
    float* __restrict__ ucy,          // (BLTOK,256): uc in, y out
    const __hip_bfloat16* __restrict__ zb, // (BLTOK,256)
    const float* __restrict__ agg,    // (4096, GCH, 64)
    const float* __restrict__ dt_w,
    const float* __restrict__ dt_b,
    const float* __restrict__ a_log,
    const float* __restrict__ Dp)
{
    int tid = threadIdx.x;
    int hw  = (blockIdx.x << 3) + (tid >> 5);
    int n   = tid & 31;
    int g   = hw & (GCH - 1);
    int bd  = hw >> 5;
    int d   = bd & 255;
    int b   = bd >> 8;

    float a = -expf(a_log[d * DSTATE + n]);
    const float* wr = dt_w + d * DTRANK;
    float w0 = wr[0], w1 = wr[1], w2 = wr[2], w3 = wr[3];
    float w4 = wr[4], w5 = wr[5], w6 = wr[6], w7 = wr[7];
    float bias = dt_b[d];
    float Dd = Dp[d];

    size_t base = (size_t)b * L_SEQ + (size_t)g * LC;
    float hst = agg[((size_t)bd * GCH + g) * 64 + 32 + n];   // h_in

    for (int t0 = 0; t0 < LC; t0 += 32) {
        size_t myt = base + t0 + n;
        const float* row = dbc + myt * 72;
        float4 r0 = *(const float4*)row;
        float4 r1 = *(const float4*)(row + 4);
        float dtr = bias + r0.x * w0 + r0.y * w1 + r0.z * w2 + r0.w * w3
                         + r1.x * w4 + r1.y * w5 + r1.z * w6 + r1.w * w7;
        float dtv = (dtr > 15.f) ? dtr : __logf(1.f + __expf(dtr));
        float uv  = ucy[myt * DINNER + d];
        float du  = dtv * uv;
        float zv  = __bfloat162float(zb[myt * DINNER + d]);
        const float* rb = dbc + (base + t0) * 72 + 8 + n;
        const float* rc = dbc + (base + t0) * 72 + 40 + n;
#pragma unroll
        for (int j = 0; j < 32; ++j) {
            float dt_j = __shfl(dtv, j, 32);
            float du_j = __shfl(du,  j, 32);
            float Bn = rb[j * 72];
            float Cn = rc[j * 72];
            float dA = __expf(dt_j * a);
            hst = hst * dA + du_j * Bn;

            float p = hst * Cn;
            p += __shfl_xor(p, 16);
            p += __shfl_xor(p, 8);
            p += __shfl_xor(p, 4);
            p += __shfl_xor(p, 2);
            p += __shfl_xor(p, 1);

            float u_j = __shfl(uv, j, 32);
            float z_j = __shfl(zv, j, 32);
            if (n == 0) {
                float yv = p + u_j * Dd;
                float sig = 1.f / (1.f + __expf(-z_j));
                ucy[(base + t0 + j) * DINNER + d] = yv * (z_j * sig);
            }
        }
    }
}

// ---------------------------------------------------------------------------
// h = LayerNorm(osum + h)   (osum already holds 0.5*(f + flip(b)))
// ---------------------------------------------------------------------------
__global__ __launch_bounds__(128) void combine_ln(
    const float* __restrict__ osum,   // (BLTOK,128)
    float* __restrict__ h,            // (BLTOK,128)
    const float* __restrict__ g,
    const float* __restrict__ be)
{
    __shared__ float red[128];
    int r = blockIdx.x;
    int c = threadIdx.x;
    size_t idx = (size_t)r * DMODEL + c;

    float v = osum[idx] + h[idx];

    red[c] = v;
    __syncthreads();
    for (int s = 64; s > 0; s >>= 1) {
        if (c < s) red[c] += red[c + s];
        __syncthreads();
    }
    float mu = red[0] * (1.f / 128.f);
    __syncthreads();
    float dv = v - mu;
    red[c] = dv * dv;
    __syncthreads();
    for (int s = 64; s > 0; s >>= 1) {
        if (c < s) red[c] += red[c + s];
        __syncthreads();
    }
    float var = red[0] * (1.f / 128.f);
    h[idx] = dv * rsqrtf(var + 1e-5f) * g[c] + be[c];
}

// ---------------------------------------------------------------------------
__global__ __launch_bounds__(128) void final_proj(
    const float* __restrict__ h,
    const float* __restrict__ pw,     // (1,128)
    const float* __restrict__ pb,     // (1,)
    float* __restrict__ out)          // (BLTOK,)
{
    __shared__ float red[128];
    int r = blockIdx.x;
    int c = threadIdx.x;
    red[c] = h[(size_t)r * DMODEL + c] * pw[c];
    __syncthreads();
    for (int s = 64; s > 0; s >>= 1) {
        if (c < s) red[c] += red[c + s];
        __syncthreads();
    }
    if (c == 0) out[r] = red[0] + pb[0];
}

// ---------------------------------------------------------------------------
extern "C" void kernel_launch(void* const* d_in, const int* in_sizes, int n_in,
                              void* d_out, int out_size, void* d_ws, size_t ws_size,
                              hipStream_t stream)
{
    const float* x    = (const float*)d_in[0];
    const float* pcw  = (const float*)d_in[1];
    const float* pcb  = (const float*)d_in[2];
    const float* inw  = (const float*)d_in[3];
    const float* cw   = (const float*)d_in[4];
    const float* cb   = (const float*)d_in[5];
    const float* xpw  = (const float*)d_in[6];
    const float* dtw  = (const float*)d_in[7];
    const float* dtb  = (const float*)d_in[8];
    const float* alog = (const float*)d_in[9];
    const float* dpar = (const float*)d_in[10];
    const float* outw = (const float*)d_in[11];
    const float* lng  = (const float*)d_in[12];
    const float* lnb  = (const float*)d_in[13];
    const float* pw   = (const float*)d_in[14];
    const float* pb   = (const float*)d_in[15];
    float* out = (float*)d_out;

    // Workspace layout — 224 MiB total (lifetime-aliased):
    //   h   : BLTOK*128 f32   persistent residual stream
    //   A   : BLTOK*256 f32   u (in_proj) -> dead after dwconv -> dbc (72 compact)
    //                         tail of A (beyond 72 cols) holds scan aggregates
    //   zb  : BLTOK*256 bf16  z gate
    //   C   : BLTOK*256 f32   uc (dwconv) -> y (scan, in-place)
    //   E   : BLTOK*128 f32   0.5*(fwd + flip(bwd)) out accumulation
    float* h  = (float*)d_ws;
    float* A  = h + (size_t)BLTOK * 128;
    __hip_bfloat16* zb = (__hip_bfloat16*)(A + (size_t)BLTOK * 256);
    float* C  = (float*)(zb + (size_t)BLTOK * 256);
    float* E  = C + (size_t)BLTOK * 256;
    // scan aggregates: 4096*GCH*64 floats = 33.5 MB, in the dead tail of A
    float* agg = A + (size_t)BLTOK * 72;

    pre_conv_gelu<<<BLTOK, 128, 0, stream>>>(x, pcw, pcb, h);

    for (int blk = 0; blk < 6; ++blk) {
        for (int dir = 0; dir < 2; ++dir) {
            int s = blk * 2 + dir;
            // in_proj: u -> A, z -> zb (bf16).  N=512, K=128
            gemm_rk<<<dim3(8, BLTOK / 64), 256, 0, stream>>>(
                h, DMODEL, inw + (size_t)s * 512 * 128, A, 0, zb,
                512, 128, dir, 1);
            // depthwise causal conv + silu: A -> C
            dwconv_silu<<<BLTOK, 256, 0, stream>>>(
                A, cw + (size_t)s * 256 * 8, cb + (size_t)s * 256, C);
            // x_proj: dbc = C @ xp_w^T -> A (compact ldc=72).  N=72, K=256
            gemm_rk<<<dim3(2, BLTOK / 64), 256, 0, stream>>>(
                C, DINNER, xpw + (size_t)s * 72 * 256, A, 72, nullptr,
                72, 256, 0, 0);
            // chunked scan: phase1 (aggregates) -> phase2 (combine) -> phase3 (y)
            scan_phase1<<<(16 * 256 * GCH) / 8, 256, 0, stream>>>(
                A, C, agg,
                dtw + (size_t)s * 256 * 8, dtb + (size_t)s * 256,
                alog + (size_t)s * 256 * 32);
            scan_phase2<<<4096 / 8, 256, 0, stream>>>(agg);
            scan_phase3<<<(16 * 256 * GCH) / 8, 256, 0, stream>>>(
                A, C, zb, agg,
                dtw + (size_t)s * 256 * 8, dtb + (size_t)s * 256,
                alog + (size_t)s * 256 * 32, dpar + (size_t)s * 256);
            // out_proj: E = y @ out_w^T (fwd) / flip-accumulate (bwd).  N=128, K=256
            gemm_rk<<<dim3(2, BLTOK / 64), 256, 0, stream>>>(
                C, DINNER, outw + (size_t)s * 128 * 256, E, 0, nullptr,
                128, 256, 0, 2 + dir);
        }
        combine_ln<<<BLTOK, 128, 0, stream>>>(
            E, h, lng + blk * 128, lnb + blk * 128);
    }

    final_proj<<<BLTOK, 128, 0, stream>>>(h, pw, pb, out);
}

// Round 4
// 8522.234 us; speedup vs baseline: 8.1557x; 2.5006x over previous
//
#include <hip/hip_runtime.h>
#include <hip/hip_bf16.h>
#include <cstdint>
#include <cstddef>

// Problem constants
#define L_SEQ   4096
#define BATCH_N 16
#define BLTOK   (BATCH_N * L_SEQ)   // 65536 tokens
#define DMODEL  128
#define DINNER  256
#define DSTATE  32
#define DTRANK  8

// Scan chunking
#define LC  64                      // chunk length
#define GCH 64                      // chunks per sequence (LC*GCH == L_SEQ)
#define LOG2E 1.44269504088896340736f

// ---------------------------------------------------------------------------
// Pre-conv (1->128 channels, k=7, same padding) + exact GELU
// ---------------------------------------------------------------------------
__global__ __launch_bounds__(128) void pre_conv_gelu(
    const float* __restrict__ x,      // (16,4096,1)
    const float* __restrict__ w,      // (128,1,7)
    const float* __restrict__ bias,   // (128,)
    float* __restrict__ h)            // (BLTOK,128)
{
    int r = blockIdx.x;
    int c = threadIdx.x;
    int b = r >> 12;
    int l = r & 4095;
    float acc = bias[c];
    const float* wp = w + c * 7;
#pragma unroll
    for (int k = 0; k < 7; ++k) {
        int ll = l + k - 3;
        if (ll >= 0 && ll < L_SEQ)
            acc += x[(size_t)(b << 12) + ll] * wp[k];
    }
    float ge = 0.5f * acc * (1.f + erff(acc * 0.70710678118654752f));
    h[(size_t)r * DMODEL + c] = ge;
}

// ---------------------------------------------------------------------------
// Tiled fp32 GEMM: acc[M,N] = A[M,K] @ W[N,K]^T
// 64x64 tile, 256 threads, 4x4 accum per thread, K-step 16.
// rev!=0: read A rows per-batch flipped (L=4096).
// Epilogue modes:
//   0: Out[row*ldc+col] = acc            (col<N guarded)       [x_proj]
//   1: col<256 -> Out[row*256+col]=acc ; col>=256 -> Zb bf16   [in_proj]
//   2: Out[row*128+col] = acc                                  [out_proj fwd]
//   3: Out[flip(row)*128+col] = 0.5*(existing + acc)           [out_proj bwd]
// ---------------------------------------------------------------------------
__global__ __launch_bounds__(256) void gemm_rk(
    const float* __restrict__ In, int lda,
    const float* __restrict__ W,      // N x K row-major
    float* __restrict__ Out, int ldc,
    __hip_bfloat16* __restrict__ Zb,
    int N, int K, int rev, int mode)
{
    __shared__ float As[16][64];
    __shared__ float Bs[16][64];

    int tid = threadIdx.x;
    int tx = tid & 15;
    int ty = tid >> 4;
    int mr = blockIdx.y * 64;
    int nc = blockIdx.x * 64;

    int lrow = tid >> 2;          // 0..63
    int kq   = (tid & 3) * 4;     // 0,4,8,12

    int gr = mr + lrow;
    if (rev) {
        int b = gr >> 12;
        int l = gr & 4095;
        gr = (b << 12) + (4095 - l);
    }
    const float* Arow = In + (size_t)gr * lda;
    int wn = nc + lrow;
    bool wvalid = (wn < N);
    const float* Wrow = W + (size_t)wn * K;

    float acc[4][4] = {};

    for (int k0 = 0; k0 < K; k0 += 16) {
        float4 av = *(const float4*)(Arow + k0 + kq);
        float4 bv = wvalid ? *(const float4*)(Wrow + k0 + kq)
                           : make_float4(0.f, 0.f, 0.f, 0.f);
        __syncthreads();
        As[kq + 0][lrow] = av.x; As[kq + 1][lrow] = av.y;
        As[kq + 2][lrow] = av.z; As[kq + 3][lrow] = av.w;
        Bs[kq + 0][lrow] = bv.x; Bs[kq + 1][lrow] = bv.y;
        Bs[kq + 2][lrow] = bv.z; Bs[kq + 3][lrow] = bv.w;
        __syncthreads();
#pragma unroll
        for (int k = 0; k < 16; ++k) {
            float4 a = *(const float4*)&As[k][ty * 4];
            float4 b = *(const float4*)&Bs[k][tx * 4];
            acc[0][0] += a.x * b.x; acc[0][1] += a.x * b.y;
            acc[0][2] += a.x * b.z; acc[0][3] += a.x * b.w;
            acc[1][0] += a.y * b.x; acc[1][1] += a.y * b.y;
            acc[1][2] += a.y * b.z; acc[1][3] += a.y * b.w;
            acc[2][0] += a.z * b.x; acc[2][1] += a.z * b.y;
            acc[2][2] += a.z * b.z; acc[2][3] += a.z * b.w;
            acc[3][0] += a.w * b.x; acc[3][1] += a.w * b.y;
            acc[3][2] += a.w * b.z; acc[3][3] += a.w * b.w;
        }
    }

#pragma unroll
    for (int i = 0; i < 4; ++i) {
        int row = mr + ty * 4 + i;
#pragma unroll
        for (int j = 0; j < 4; ++j) {
            int col = nc + tx * 4 + j;
            float v = acc[i][j];
            if (mode == 0) {
                if (col < N) Out[(size_t)row * ldc + col] = v;
            } else if (mode == 1) {
                if (col < 256) Out[(size_t)row * 256 + col] = v;
                else           Zb[(size_t)row * 256 + (col - 256)] = __float2bfloat16(v);
            } else if (mode == 2) {
                Out[(size_t)row * 128 + col] = v;
            } else {
                int b = row >> 12, l = row & 4095;
                size_t o = ((size_t)(b << 12) + (4095 - l)) * 128 + col;
                Out[o] = 0.5f * (Out[o] + v);
            }
        }
    }
}

// ---------------------------------------------------------------------------
// Depthwise causal conv (k=8, pad (7,0)) + SiLU, register sliding window.
// Each thread: one channel d, 32 consecutive timesteps.
// ---------------------------------------------------------------------------
__global__ __launch_bounds__(256) void dwconv_silu(
    const float* __restrict__ u,      // (BLTOK,256)
    const float* __restrict__ cw,     // (256,1,8)
    const float* __restrict__ cb,     // (256,)
    float* __restrict__ uc)           // (BLTOK,256)
{
    int b  = blockIdx.x >> 7;         // 16 batches
    int lt = blockIdx.x & 127;        // 128 tiles of 32
    int l0 = lt * 32;
    int d  = threadIdx.x;

    float wv[8];
    const float* wp = cw + d * 8;
#pragma unroll
    for (int k = 0; k < 8; ++k) wv[k] = wp[k];
    float bias = cb[d];

    size_t rowb = (size_t)(b << 12);
    float win[8];
#pragma unroll
    for (int j = 0; j < 7; ++j) {
        int ll = l0 - 7 + j;
        win[j] = (ll >= 0) ? u[(rowb + ll) * DINNER + d] : 0.f;
    }
#pragma unroll
    for (int i = 0; i < 32; ++i) {
        int l = l0 + i;
        win[7] = u[(rowb + l) * DINNER + d];
        float acc = bias;
#pragma unroll
        for (int j = 0; j < 8; ++j) acc += win[j] * wv[j];
        float s = acc / (1.f + __expf(-acc));
        uc[(rowb + l) * DINNER + d] = s;
#pragma unroll
        for (int j = 0; j < 7; ++j) win[j] = win[j + 1];
    }
}

// ---------------------------------------------------------------------------
// Chunked selective scan, lane = channel d, h[32] states in registers.
// Phase 1: per-chunk zero-init local scan -> h_end[32] and S = sum(dt).
// Block = 256 threads = one (b,g) chunk covering all 256 d.
// aggh layout: [((b*GCH+g)*32+n)*256 + d]  (d-coalesced)
// aggs layout: [(b*GCH+g)*256 + d]
// ---------------------------------------------------------------------------
__global__ __launch_bounds__(256) void scan_phase1(
    const float* __restrict__ dbc,    // (BLTOK,72) compact
    const float* __restrict__ u,      // (BLTOK,256)
    float* __restrict__ aggh,
    float* __restrict__ aggs,
    const float* __restrict__ dt_w,   // (256,8)
    const float* __restrict__ dt_b,   // (256,)
    const float* __restrict__ a_log)  // (256,32)
{
    __shared__ __align__(16) float sh[LC * 72];
    int bg = blockIdx.x;
    int b  = bg >> 6;
    int g  = bg & (GCH - 1);
    int d  = threadIdx.x;

    size_t base = (size_t)b * L_SEQ + (size_t)g * LC;
    const float* src = dbc + base * 72;
    for (int i = d; i < LC * 72; i += 256) sh[i] = src[i];

    const float* wr = dt_w + d * DTRANK;
    float w0 = wr[0], w1 = wr[1], w2 = wr[2], w3 = wr[3];
    float w4 = wr[4], w5 = wr[5], w6 = wr[6], w7 = wr[7];
    float bias = dt_b[d];

    float al2[32];
    {
        const float4* ar = (const float4*)(a_log + d * DSTATE);
#pragma unroll
        for (int k = 0; k < 8; ++k) {
            float4 v = ar[k];
            al2[4 * k + 0] = -__expf(v.x) * LOG2E;
            al2[4 * k + 1] = -__expf(v.y) * LOG2E;
            al2[4 * k + 2] = -__expf(v.z) * LOG2E;
            al2[4 * k + 3] = -__expf(v.w) * LOG2E;
        }
    }
    __syncthreads();

    float h[32];
#pragma unroll
    for (int n = 0; n < 32; ++n) h[n] = 0.f;
    float S = 0.f;

    for (int t = 0; t < LC; ++t) {
        const float* row = sh + t * 72;
        float4 r0 = *(const float4*)row;
        float4 r1 = *(const float4*)(row + 4);
        float dtr = bias + r0.x * w0 + r0.y * w1 + r0.z * w2 + r0.w * w3
                         + r1.x * w4 + r1.y * w5 + r1.z * w6 + r1.w * w7;
        float dtv = (dtr > 15.f) ? dtr : __logf(1.f + __expf(dtr));
        S += dtv;
        float du = dtv * u[(base + t) * DINNER + d];
#pragma unroll
        for (int n = 0; n < 32; n += 4) {
            float4 Bv = *(const float4*)(row + 8 + n);
            h[n + 0] = h[n + 0] * exp2f(dtv * al2[n + 0]) + du * Bv.x;
            h[n + 1] = h[n + 1] * exp2f(dtv * al2[n + 1]) + du * Bv.y;
            h[n + 2] = h[n + 2] * exp2f(dtv * al2[n + 2]) + du * Bv.z;
            h[n + 3] = h[n + 3] * exp2f(dtv * al2[n + 3]) + du * Bv.w;
        }
    }

    size_t ob = ((size_t)(b * GCH + g) * 32) * 256 + d;
#pragma unroll
    for (int n = 0; n < 32; ++n) aggh[ob + (size_t)n * 256] = h[n];
    aggs[(size_t)(b * GCH + g) * 256 + d] = S;
}

// ---------------------------------------------------------------------------
// Phase 2: serial combine across chunks.  P_n = exp(a_n * S_g).
// Grid = 16*32 blocks (b,n), 256 threads (d).  Overwrites aggh with h_in.
// ---------------------------------------------------------------------------
__global__ __launch_bounds__(256) void scan_phase2(
    float* __restrict__ aggh,
    const float* __restrict__ aggs,
    const float* __restrict__ a_log)
{
    int b = blockIdx.x >> 5;
    int n = blockIdx.x & 31;
    int d = threadIdx.x;

    float a = -__expf(a_log[d * DSTATE + n]);
    float hrun = 0.f;
    for (int g = 0; g < GCH; ++g) {
        size_t os = (size_t)(b * GCH + g) * 256 + d;
        size_t oh = ((size_t)(b * GCH + g) * 32 + n) * 256 + d;
        float S  = aggs[os];
        float he = aggh[oh];
        aggh[oh] = hrun;                  // h_in for chunk g
        hrun = hrun * __expf(a * S) + he;
    }
}

// ---------------------------------------------------------------------------
// Phase 3: local scan seeded with h_in; fused y = <h,C>, D skip, silu(z).
// y overwrites uc in place (thread-local read-before-write).
// ---------------------------------------------------------------------------
__global__ __launch_bounds__(256) void scan_phase3(
    const float* __restrict__ dbc,    // (BLTOK,72)
    float* __restrict__ ucy,          // (BLTOK,256): uc in, y out
    const __hip_bfloat16* __restrict__ zb, // (BLTOK,256)
    const float* __restrict__ aggh,
    const float* __restrict__ dt_w,
    const float* __restrict__ dt_b,
    const float* __restrict__ a_log,
    const float* __restrict__ Dp)
{
    __shared__ __align__(16) float sh[LC * 72];
    int bg = blockIdx.x;
    int b  = bg >> 6;
    int g  = bg & (GCH - 1);
    int d  = threadIdx.x;

    size_t base = (size_t)b * L_SEQ + (size_t)g * LC;
    const float* src = dbc + base * 72;
    for (int i = d; i < LC * 72; i += 256) sh[i] = src[i];

    const float* wr = dt_w + d * DTRANK;
    float w0 = wr[0], w1 = wr[1], w2 = wr[2], w3 = wr[3];
    float w4 = wr[4], w5 = wr[5], w6 = wr[6], w7 = wr[7];
    float bias = dt_b[d];
    float Dd = Dp[d];

    float al2[32];
    {
        const float4* ar = (const float4*)(a_log + d * DSTATE);
#pragma unroll
        for (int k = 0; k < 8; ++k) {
            float4 v = ar[k];
            al2[4 * k + 0] = -__expf(v.x) * LOG2E;
            al2[4 * k + 1] = -__expf(v.y) * LOG2E;
            al2[4 * k + 2] = -__expf(v.z) * LOG2E;
            al2[4 * k + 3] = -__expf(v.w) * LOG2E;
        }
    }

    float h[32];
    size_t ob = ((size_t)(b * GCH + g) * 32) * 256 + d;
#pragma unroll
    for (int n = 0; n < 32; ++n) h[n] = aggh[ob + (size_t)n * 256];

    __syncthreads();

    for (int t = 0; t < LC; ++t) {
        const float* row = sh + t * 72;
        float4 r0 = *(const float4*)row;
        float4 r1 = *(const float4*)(row + 4);
        float dtr = bias + r0.x * w0 + r0.y * w1 + r0.z * w2 + r0.w * w3
                         + r1.x * w4 + r1.y * w5 + r1.z * w6 + r1.w * w7;
        float dtv = (dtr > 15.f) ? dtr : __logf(1.f + __expf(dtr));
        float uv = ucy[(base + t) * DINNER + d];
        float du = dtv * uv;
        float zv = __bfloat162float(zb[(base + t) * DINNER + d]);

        float y = 0.f;
#pragma unroll
        for (int n = 0; n < 32; n += 4) {
            float4 Bv = *(const float4*)(row + 8 + n);
            float4 Cv = *(const float4*)(row + 40 + n);
            h[n + 0] = h[n + 0] * exp2f(dtv * al2[n + 0]) + du * Bv.x;
            h[n + 1] = h[n + 1] * exp2f(dtv * al2[n + 1]) + du * Bv.y;
            h[n + 2] = h[n + 2] * exp2f(dtv * al2[n + 2]) + du * Bv.z;
            h[n + 3] = h[n + 3] * exp2f(dtv * al2[n + 3]) + du * Bv.w;
            y += h[n + 0] * Cv.x + h[n + 1] * Cv.y
               + h[n + 2] * Cv.z + h[n + 3] * Cv.w;
        }
        float yv = y + uv * Dd;
        float sig = 1.f / (1.f + __expf(-zv));
        ucy[(base + t) * DINNER + d] = yv * (zv * sig);
    }
}

// ---------------------------------------------------------------------------
// h = LayerNorm(osum + h)   (osum already holds 0.5*(f + flip(b)))
// ---------------------------------------------------------------------------
__global__ __launch_bounds__(128) void combine_ln(
    const float* __restrict__ osum,   // (BLTOK,128)
    float* __restrict__ h,            // (BLTOK,128)
    const float* __restrict__ g,
    const float* __restrict__ be)
{
    __shared__ float red[128];
    int r = blockIdx.x;
    int c = threadIdx.x;
    size_t idx = (size_t)r * DMODEL + c;

    float v = osum[idx] + h[idx];

    red[c] = v;
    __syncthreads();
    for (int s = 64; s > 0; s >>= 1) {
        if (c < s) red[c] += red[c + s];
        __syncthreads();
    }
    float mu = red[0] * (1.f / 128.f);
    __syncthreads();
    float dv = v - mu;
    red[c] = dv * dv;
    __syncthreads();
    for (int s = 64; s > 0; s >>= 1) {
        if (c < s) red[c] += red[c + s];
        __syncthreads();
    }
    float var = red[0] * (1.f / 128.f);
    h[idx] = dv * rsqrtf(var + 1e-5f) * g[c] + be[c];
}

// ---------------------------------------------------------------------------
__global__ __launch_bounds__(128) void final_proj(
    const float* __restrict__ h,
    const float* __restrict__ pw,     // (1,128)
    const float* __restrict__ pb,     // (1,)
    float* __restrict__ out)          // (BLTOK,)
{
    __shared__ float red[128];
    int r = blockIdx.x;
    int c = threadIdx.x;
    red[c] = h[(size_t)r * DMODEL + c] * pw[c];
    __syncthreads();
    for (int s = 64; s > 0; s >>= 1) {
        if (c < s) red[c] += red[c + s];
        __syncthreads();
    }
    if (c == 0) out[r] = red[0] + pb[0];
}

// ---------------------------------------------------------------------------
extern "C" void kernel_launch(void* const* d_in, const int* in_sizes, int n_in,
                              void* d_out, int out_size, void* d_ws, size_t ws_size,
                              hipStream_t stream)
{
    const float* x    = (const float*)d_in[0];
    const float* pcw  = (const float*)d_in[1];
    const float* pcb  = (const float*)d_in[2];
    const float* inw  = (const float*)d_in[3];
    const float* cw   = (const float*)d_in[4];
    const float* cb   = (const float*)d_in[5];
    const float* xpw  = (const float*)d_in[6];
    const float* dtw  = (const float*)d_in[7];
    const float* dtb  = (const float*)d_in[8];
    const float* alog = (const float*)d_in[9];
    const float* dpar = (const float*)d_in[10];
    const float* outw = (const float*)d_in[11];
    const float* lng  = (const float*)d_in[12];
    const float* lnb  = (const float*)d_in[13];
    const float* pw   = (const float*)d_in[14];
    const float* pb   = (const float*)d_in[15];
    float* out = (float*)d_out;

    // Workspace layout — ~224 MiB total (lifetime-aliased):
    //   h   : BLTOK*128 f32   persistent residual stream
    //   A   : BLTOK*256 f32   u (in_proj) -> dead after dwconv -> dbc (72 cols)
    //                         tail holds scan aggregates (aggh 33.5MB + aggs 1MB)
    //   zb  : BLTOK*256 bf16  z gate
    //   C   : BLTOK*256 f32   uc (dwconv) -> y (scan, in-place)
    //   E   : BLTOK*128 f32   0.5*(fwd + flip(bwd)) out accumulation
    float* h  = (float*)d_ws;
    float* A  = h + (size_t)BLTOK * 128;
    __hip_bfloat16* zb = (__hip_bfloat16*)(A + (size_t)BLTOK * 256);
    float* C  = (float*)(zb + (size_t)BLTOK * 256);
    float* E  = C + (size_t)BLTOK * 256;
    float* aggh = A + (size_t)BLTOK * 72;                       // 16*GCH*32*256 floats
    float* aggs = aggh + (size_t)16 * GCH * 32 * 256;           // 16*GCH*256 floats

    pre_conv_gelu<<<BLTOK, 128, 0, stream>>>(x, pcw, pcb, h);

    for (int blk = 0; blk < 6; ++blk) {
        for (int dir = 0; dir < 2; ++dir) {
            int s = blk * 2 + dir;
            // in_proj: u -> A, z -> zb (bf16).  N=512, K=128
            gemm_rk<<<dim3(8, BLTOK / 64), 256, 0, stream>>>(
                h, DMODEL, inw + (size_t)s * 512 * 128, A, 0, zb,
                512, 128, dir, 1);
            // depthwise causal conv + silu: A -> C
            dwconv_silu<<<16 * 128, 256, 0, stream>>>(
                A, cw + (size_t)s * 256 * 8, cb + (size_t)s * 256, C);
            // x_proj: dbc = C @ xp_w^T -> A (compact ldc=72).  N=72, K=256
            gemm_rk<<<dim3(2, BLTOK / 64), 256, 0, stream>>>(
                C, DINNER, xpw + (size_t)s * 72 * 256, A, 72, nullptr,
                72, 256, 0, 0);
            // chunked scan
            scan_phase1<<<16 * GCH, 256, 0, stream>>>(
                A, C, aggh, aggs,
                dtw + (size_t)s * 256 * 8, dtb + (size_t)s * 256,
                alog + (size_t)s * 256 * 32);
            scan_phase2<<<16 * 32, 256, 0, stream>>>(
                aggh, aggs, alog + (size_t)s * 256 * 32);
            scan_phase3<<<16 * GCH, 256, 0, stream>>>(
                A, C, zb, aggh,
                dtw + (size_t)s * 256 * 8, dtb + (size_t)s * 256,
                alog + (size_t)s * 256 * 32, dpar + (size_t)s * 256);
            // out_proj: E = y @ out_w^T (fwd) / flip-accumulate (bwd).  N=128, K=256
            gemm_rk<<<dim3(2, BLTOK / 64), 256, 0, stream>>>(
                C, DINNER, outw + (size_t)s * 128 * 256, E, 0, nullptr,
                128, 256, 0, 2 + dir);
        }
        combine_ln<<<BLTOK, 128, 0, stream>>>(
            E, h, lng + blk * 128, lnb + blk * 128);
    }

    final_proj<<<BLTOK, 128, 0, stream>>>(h, pw, pb, out);
}

// Round 6
// 6218.410 us; speedup vs baseline: 11.1772x; 1.3705x over previous
//
#include <hip/hip_runtime.h>
#include <hip/hip_bf16.h>
#include <cstdint>
#include <cstddef>

// Problem constants
#define L_SEQ   4096
#define BATCH_N 16
#define BLTOK   (BATCH_N * L_SEQ)   // 65536 tokens
#define DMODEL  128
#define DINNER  256
#define DSTATE  32
#define DTRANK  8

// Scan chunking
#define LC  64                      // chunk length
#define GCH 64                      // chunks per sequence
#define LOG2E 1.44269504088896340736f

typedef _Float16 half8 __attribute__((ext_vector_type(8)));
typedef float    floatx4 __attribute__((ext_vector_type(4)));

#define LDSW 40   // LDS row stride in halves (32 data + 8 pad; 80B = 16B-aligned, 2-way banks = free)

// ---------------------------------------------------------------------------
// Pre-conv (1->128 channels, k=7, same padding) + exact GELU.  Writes fp32 + fp16.
// ---------------------------------------------------------------------------
__global__ __launch_bounds__(128) void pre_conv_gelu(
    const float* __restrict__ x,      // (16,4096,1)
    const float* __restrict__ w,      // (128,1,7)
    const float* __restrict__ bias,   // (128,)
    float* __restrict__ h,            // (BLTOK,128)
    _Float16* __restrict__ hb)        // (BLTOK,128)
{
    int r = blockIdx.x;
    int c = threadIdx.x;
    int b = r >> 12;
    int l = r & 4095;
    float acc = bias[c];
    const float* wp = w + c * 7;
#pragma unroll
    for (int k = 0; k < 7; ++k) {
        int ll = l + k - 3;
        if (ll >= 0 && ll < L_SEQ)
            acc += x[(size_t)(b << 12) + ll] * wp[k];
    }
    float ge = 0.5f * acc * (1.f + erff(acc * 0.70710678118654752f));
    h[(size_t)r * DMODEL + c]  = ge;
    hb[(size_t)r * DMODEL + c] = (_Float16)ge;
}

// ---------------------------------------------------------------------------
// Convert fp32 weights -> fp16 (runs once per launch; deterministic).
// ---------------------------------------------------------------------------
__global__ __launch_bounds__(256) void cvt_weights(
    const float* __restrict__ inw,  _Float16* __restrict__ inwh,   // 12*512*128
    const float* __restrict__ xpw,  _Float16* __restrict__ xpwh,   // 12*72*256
    const float* __restrict__ outw, _Float16* __restrict__ outwh)  // 12*128*256
{
    int i = blockIdx.x * 256 + threadIdx.x;
    if (i < 12 * 512 * 128) inwh[i]  = (_Float16)inw[i];
    if (i < 12 * 72 * 256)  xpwh[i]  = (_Float16)xpw[i];
    if (i < 12 * 128 * 256) outwh[i] = (_Float16)outw[i];
}

// ---------------------------------------------------------------------------
// MFMA fp16 GEMM: C[M,N] = A[M,K] @ W[N,K]^T, fp32 accumulate.
// 64x64 tile, 256 threads = 4 waves; wave w computes rows 16w..16w+15 x all
// 64 cols via 4 mfma_f32_16x16x32_f16.  K multiple of 32.
// rev!=0: A rows read per-batch flipped (L=4096).
// Epilogue modes:
//   0: x_proj  -> Out[row*72+col], col<N guarded
//   1: in_proj -> col<256: Out[row*256+col] (u fp32); col>=256: Zb bf16 (z)
//   2: out_proj fwd -> Out[row*128+col]
//   3: out_proj bwd -> Out[flip(row)*128+col] = 0.5*(existing + acc)
// ---------------------------------------------------------------------------
__global__ __launch_bounds__(256) void gemm_mfma(
    const _Float16* __restrict__ A, int lda,
    const _Float16* __restrict__ W, int ldw,   // N x ldw, K contiguous
    float* __restrict__ Out,
    __hip_bfloat16* __restrict__ Zb,
    int N, int K, int rev, int mode)
{
    __shared__ __align__(16) _Float16 As[64 * LDSW];
    __shared__ __align__(16) _Float16 Ws[64 * LDSW];

    int tid  = threadIdx.x;
    int wave = tid >> 6;
    int lane = tid & 63;
    int m0 = blockIdx.y * 64;
    int n0 = blockIdx.x * 64;

    // staging: thread t loads 16B of row (t>>2), k-chunk (t&3)*8
    int srow = tid >> 2;
    int skc  = (tid & 3) * 8;

    int garow = m0 + srow;
    if (rev) { int bb = garow >> 12; int ll = garow & 4095; garow = (bb << 12) + (4095 - ll); }
    const _Float16* Aptr = A + (size_t)garow * lda + skc;
    int wrow = n0 + srow;
    bool wok = (wrow < N);
    const _Float16* Wptr = W + (size_t)(wok ? wrow : 0) * ldw + skc;

    int lr = lane & 15;          // m (A) / n (B) / col (C)
    int lk = (lane >> 4) * 8;    // k offset within 32
    int soff = srow * LDSW + skc;
    int aoff = (16 * wave + lr) * LDSW + lk;

    floatx4 acc0 = {0.f, 0.f, 0.f, 0.f};
    floatx4 acc1 = acc0, acc2 = acc0, acc3 = acc0;

    for (int k0 = 0; k0 < K; k0 += 32) {
        half8 av = *(const half8*)(Aptr + k0);
        half8 bv = {};
        if (wok) bv = *(const half8*)(Wptr + k0);
        __syncthreads();
        *(half8*)&As[soff] = av;
        *(half8*)&Ws[soff] = bv;
        __syncthreads();
        half8 af = *(const half8*)&As[aoff];
        half8 b0 = *(const half8*)&Ws[( 0 + lr) * LDSW + lk];
        half8 b1 = *(const half8*)&Ws[(16 + lr) * LDSW + lk];
        half8 b2 = *(const half8*)&Ws[(32 + lr) * LDSW + lk];
        half8 b3 = *(const half8*)&Ws[(48 + lr) * LDSW + lk];
        acc0 = __builtin_amdgcn_mfma_f32_16x16x32_f16(af, b0, acc0, 0, 0, 0);
        acc1 = __builtin_amdgcn_mfma_f32_16x16x32_f16(af, b1, acc1, 0, 0, 0);
        acc2 = __builtin_amdgcn_mfma_f32_16x16x32_f16(af, b2, acc2, 0, 0, 0);
        acc3 = __builtin_amdgcn_mfma_f32_16x16x32_f16(af, b3, acc3, 0, 0, 0);
    }

    // C/D layout: col = lane&15, row = (lane>>4)*4 + reg
    int orow = m0 + 16 * wave + (lane >> 4) * 4;
    floatx4 av4[4] = {acc0, acc1, acc2, acc3};
#pragma unroll
    for (int jb = 0; jb < 4; ++jb) {
        int col = n0 + jb * 16 + lr;
#pragma unroll
        for (int r = 0; r < 4; ++r) {
            int row = orow + r;
            float v = av4[jb][r];
            if (mode == 0) {
                if (col < N) Out[(size_t)row * 72 + col] = v;
            } else if (mode == 1) {
                if (col < 256) Out[(size_t)row * 256 + col] = v;
                else Zb[(size_t)row * 256 + (col - 256)] = __float2bfloat16(v);
            } else if (mode == 2) {
                Out[(size_t)row * 128 + col] = v;
            } else {
                int bb = row >> 12, ll = row & 4095;
                size_t o = ((size_t)(bb << 12) + (4095 - ll)) * 128 + col;
                Out[o] = 0.5f * (Out[o] + v);
            }
        }
    }
}

// ---------------------------------------------------------------------------
// Depthwise causal conv (k=8, pad (7,0)) + SiLU, register sliding window.
// Reads u fp32 (stride 256), writes uc fp16.
// ---------------------------------------------------------------------------
__global__ __launch_bounds__(256) void dwconv_silu(
    const float* __restrict__ u,      // (BLTOK,256)
    const float* __restrict__ cw,     // (256,1,8)
    const float* __restrict__ cb,     // (256,)
    _Float16* __restrict__ uc)        // (BLTOK,256)
{
    int b  = blockIdx.x >> 7;
    int lt = blockIdx.x & 127;
    int l0 = lt * 32;
    int d  = threadIdx.x;

    float wv[8];
    const float* wp = cw + d * 8;
#pragma unroll
    for (int k = 0; k < 8; ++k) wv[k] = wp[k];
    float bias = cb[d];

    size_t rowb = (size_t)(b << 12);
    float win[8];
#pragma unroll
    for (int j = 0; j < 7; ++j) {
        int ll = l0 - 7 + j;
        win[j] = (ll >= 0) ? u[(rowb + ll) * DINNER + d] : 0.f;
    }
#pragma unroll
    for (int i = 0; i < 32; ++i) {
        int l = l0 + i;
        win[7] = u[(rowb + l) * DINNER + d];
        float acc = bias;
#pragma unroll
        for (int j = 0; j < 8; ++j) acc += win[j] * wv[j];
        float s = acc / (1.f + __expf(-acc));
        uc[(rowb + l) * DINNER + d] = (_Float16)s;
#pragma unroll
        for (int j = 0; j < 7; ++j) win[j] = win[j + 1];
    }
}

// ---------------------------------------------------------------------------
// Chunked selective scan, lane = channel d, h[32] states in registers.
// Phase 1: zero-init local scan -> h_end[32], S = sum(dt).
// ---------------------------------------------------------------------------
__global__ __launch_bounds__(256) void scan_phase1(
    const float* __restrict__ dbc,    // (BLTOK,72)
    const _Float16* __restrict__ u,   // (BLTOK,256)
    float* __restrict__ aggh,
    float* __restrict__ aggs,
    const float* __restrict__ dt_w,
    const float* __restrict__ dt_b,
    const float* __restrict__ a_log)
{
    __shared__ __align__(16) float sh[LC * 72];
    int bg = blockIdx.x;
    int b  = bg >> 6;
    int g  = bg & (GCH - 1);
    int d  = threadIdx.x;

    size_t base = (size_t)b * L_SEQ + (size_t)g * LC;
    const float* src = dbc + base * 72;
    for (int i = d; i < LC * 72; i += 256) sh[i] = src[i];

    const float* wr = dt_w + d * DTRANK;
    float w0 = wr[0], w1 = wr[1], w2 = wr[2], w3 = wr[3];
    float w4 = wr[4], w5 = wr[5], w6 = wr[6], w7 = wr[7];
    float bias = dt_b[d];

    float al2[32];
    {
        const float4* ar = (const float4*)(a_log + d * DSTATE);
#pragma unroll
        for (int k = 0; k < 8; ++k) {
            float4 v = ar[k];
            al2[4 * k + 0] = -__expf(v.x) * LOG2E;
            al2[4 * k + 1] = -__expf(v.y) * LOG2E;
            al2[4 * k + 2] = -__expf(v.z) * LOG2E;
            al2[4 * k + 3] = -__expf(v.w) * LOG2E;
        }
    }
    __syncthreads();

    float h[32];
#pragma unroll
    for (int n = 0; n < 32; ++n) h[n] = 0.f;
    float S = 0.f;

    for (int t = 0; t < LC; ++t) {
        const float* row = sh + t * 72;
        float4 r0 = *(const float4*)row;
        float4 r1 = *(const float4*)(row + 4);
        float dtr = bias + r0.x * w0 + r0.y * w1 + r0.z * w2 + r0.w * w3
                         + r1.x * w4 + r1.y * w5 + r1.z * w6 + r1.w * w7;
        float dtv = (dtr > 15.f) ? dtr : __logf(1.f + __expf(dtr));
        S += dtv;
        float du = dtv * (float)u[(base + t) * DINNER + d];
#pragma unroll
        for (int n = 0; n < 32; n += 4) {
            float4 Bv = *(const float4*)(row + 8 + n);
            h[n + 0] = h[n + 0] * exp2f(dtv * al2[n + 0]) + du * Bv.x;
            h[n + 1] = h[n + 1] * exp2f(dtv * al2[n + 1]) + du * Bv.y;
            h[n + 2] = h[n + 2] * exp2f(dtv * al2[n + 2]) + du * Bv.z;
            h[n + 3] = h[n + 3] * exp2f(dtv * al2[n + 3]) + du * Bv.w;
        }
    }

    size_t ob = ((size_t)(b * GCH + g) * 32) * 256 + d;
#pragma unroll
    for (int n = 0; n < 32; ++n) aggh[ob + (size_t)n * 256] = h[n];
    aggs[(size_t)(b * GCH + g) * 256 + d] = S;
}

// ---------------------------------------------------------------------------
// Phase 2: serial combine across chunks.  P_n = exp(a_n * S_g).
// ---------------------------------------------------------------------------
__global__ __launch_bounds__(256) void scan_phase2(
    float* __restrict__ aggh,
    const float* __restrict__ aggs,
    const float* __restrict__ a_log)
{
    int b = blockIdx.x >> 5;
    int n = blockIdx.x & 31;
    int d = threadIdx.x;

    float a = -__expf(a_log[d * DSTATE + n]);
    float hrun = 0.f;
    for (int g = 0; g < GCH; ++g) {
        size_t os = (size_t)(b * GCH + g) * 256 + d;
        size_t oh = ((size_t)(b * GCH + g) * 32 + n) * 256 + d;
        float S  = aggs[os];
        float he = aggh[oh];
        aggh[oh] = hrun;
        hrun = hrun * __expf(a * S) + he;
    }
}

// ---------------------------------------------------------------------------
// Phase 3: local scan seeded with h_in; fused y = <h,C>, D skip, silu(z).
// Reads z (bf16) and writes y (fp16) to the SAME buffer slot (thread-local
// read-before-write).
// ---------------------------------------------------------------------------
__global__ __launch_bounds__(256) void scan_phase3(
    const float* __restrict__ dbc,     // (BLTOK,72)
    const _Float16* __restrict__ u,    // (BLTOK,256)
    __hip_bfloat16* __restrict__ zy,   // (BLTOK,256): z bf16 in, y fp16 out
    const float* __restrict__ aggh,
    const float* __restrict__ dt_w,
    const float* __restrict__ dt_b,
    const float* __restrict__ a_log,
    const float* __restrict__ Dp)
{
    __shared__ __align__(16) float sh[LC * 72];
    int bg = blockIdx.x;
    int b  = bg >> 6;
    int g  = bg & (GCH - 1);
    int d  = threadIdx.x;

    size_t base = (size_t)b * L_SEQ + (size_t)g * LC;
    const float* src = dbc + base * 72;
    for (int i = d; i < LC * 72; i += 256) sh[i] = src[i];

    const float* wr = dt_w + d * DTRANK;
    float w0 = wr[0], w1 = wr[1], w2 = wr[2], w3 = wr[3];
    float w4 = wr[4], w5 = wr[5], w6 = wr[6], w7 = wr[7];
    float bias = dt_b[d];
    float Dd = Dp[d];

    float al2[32];
    {
        const float4* ar = (const float4*)(a_log + d * DSTATE);
#pragma unroll
        for (int k = 0; k < 8; ++k) {
            float4 v = ar[k];
            al2[4 * k + 0] = -__expf(v.x) * LOG2E;
            al2[4 * k + 1] = -__expf(v.y) * LOG2E;
            al2[4 * k + 2] = -__expf(v.z) * LOG2E;
            al2[4 * k + 3] = -__expf(v.w) * LOG2E;
        }
    }

    float h[32];
    size_t ob = ((size_t)(b * GCH + g) * 32) * 256 + d;
#pragma unroll
    for (int n = 0; n < 32; ++n) h[n] = aggh[ob + (size_t)n * 256];

    __syncthreads();

    _Float16* yo = (_Float16*)zy;

    for (int t = 0; t < LC; ++t) {
        const float* row = sh + t * 72;
        float4 r0 = *(const float4*)row;
        float4 r1 = *(const float4*)(row + 4);
        float dtr = bias + r0.x * w0 + r0.y * w1 + r0.z * w2 + r0.w * w3
                         + r1.x * w4 + r1.y * w5 + r1.z * w6 + r1.w * w7;
        float dtv = (dtr > 15.f) ? dtr : __logf(1.f + __expf(dtr));
        float uv = (float)u[(base + t) * DINNER + d];
        float du = dtv * uv;
        float zv = __bfloat162float(zy[(base + t) * DINNER + d]);

        float y = 0.f;
#pragma unroll
        for (int n = 0; n < 32; n += 4) {
            float4 Bv = *(const float4*)(row + 8 + n);
            float4 Cv = *(const float4*)(row + 40 + n);
            h[n + 0] = h[n + 0] * exp2f(dtv * al2[n + 0]) + du * Bv.x;
            h[n + 1] = h[n + 1] * exp2f(dtv * al2[n + 1]) + du * Bv.y;
            h[n + 2] = h[n + 2] * exp2f(dtv * al2[n + 2]) + du * Bv.z;
            h[n + 3] = h[n + 3] * exp2f(dtv * al2[n + 3]) + du * Bv.w;
            y += h[n + 0] * Cv.x + h[n + 1] * Cv.y
               + h[n + 2] * Cv.z + h[n + 3] * Cv.w;
        }
        float yv = y + uv * Dd;
        float sig = 1.f / (1.f + __expf(-zv));
        yo[(base + t) * DINNER + d] = (_Float16)(yv * (zv * sig));
    }
}

// ---------------------------------------------------------------------------
// h = LayerNorm(osum + h); writes fp32 h and fp16 hb
// ---------------------------------------------------------------------------
__global__ __launch_bounds__(128) void combine_ln(
    const float* __restrict__ osum,   // (BLTOK,128)
    float* __restrict__ h,            // (BLTOK,128)
    _Float16* __restrict__ hb,        // (BLTOK,128)
    const float* __restrict__ g,
    const float* __restrict__ be)
{
    __shared__ float red[128];
    int r = blockIdx.x;
    int c = threadIdx.x;
    size_t idx = (size_t)r * DMODEL + c;

    float v = osum[idx] + h[idx];

    red[c] = v;
    __syncthreads();
    for (int s = 64; s > 0; s >>= 1) {
        if (c < s) red[c] += red[c + s];
        __syncthreads();
    }
    float mu = red[0] * (1.f / 128.f);
    __syncthreads();
    float dv = v - mu;
    red[c] = dv * dv;
    __syncthreads();
    for (int s = 64; s > 0; s >>= 1) {
        if (c < s) red[c] += red[c + s];
        __syncthreads();
    }
    float var = red[0] * (1.f / 128.f);
    float o = dv * rsqrtf(var + 1e-5f) * g[c] + be[c];
    h[idx]  = o;
    hb[idx] = (_Float16)o;
}

// ---------------------------------------------------------------------------
__global__ __launch_bounds__(128) void final_proj(
    const float* __restrict__ h,
    const float* __restrict__ pw,     // (1,128)
    const float* __restrict__ pb,     // (1,)
    float* __restrict__ out)          // (BLTOK,)
{
    __shared__ float red[128];
    int r = blockIdx.x;
    int c = threadIdx.x;
    red[c] = h[(size_t)r * DMODEL + c] * pw[c];
    __syncthreads();
    for (int s = 64; s > 0; s >>= 1) {
        if (c < s) red[c] += red[c + s];
        __syncthreads();
    }
    if (c == 0) out[r] = red[0] + pb[0];
}

// ---------------------------------------------------------------------------
extern "C" void kernel_launch(void* const* d_in, const int* in_sizes, int n_in,
                              void* d_out, int out_size, void* d_ws, size_t ws_size,
                              hipStream_t stream)
{
    const float* x    = (const float*)d_in[0];
    const float* pcw  = (const float*)d_in[1];
    const float* pcb  = (const float*)d_in[2];
    const float* inw  = (const float*)d_in[3];
    const float* cw   = (const float*)d_in[4];
    const float* cb   = (const float*)d_in[5];
    const float* xpw  = (const float*)d_in[6];
    const float* dtw  = (const float*)d_in[7];
    const float* dtb  = (const float*)d_in[8];
    const float* alog = (const float*)d_in[9];
    const float* dpar = (const float*)d_in[10];
    const float* outw = (const float*)d_in[11];
    const float* lng  = (const float*)d_in[12];
    const float* lnb  = (const float*)d_in[13];
    const float* pw   = (const float*)d_in[14];
    const float* pb   = (const float*)d_in[15];
    float* out = (float*)d_out;

    // Workspace layout (~211 MiB, lifetime-aliased):
    //   h    : BLTOK*128 f32   residual stream
    //   A    : BLTOK*256 f32   u fp32 (in_proj) -> dbc (72 cols) + agg tail
    //   zy   : BLTOK*256 2B    z bf16 (in_proj) -> y fp16 (scan, in-place)
    //   ucb  : BLTOK*256 f16   conv output (scan input)
    //   hb   : BLTOK*128 f16   fp16 shadow of h (GEMM input)
    //   E    : BLTOK*128 f32   0.5*(fwd + flip(bwd)) accumulation
    //   w16  : fp16 weights (inwh | xpwh | outwh)
    float* h  = (float*)d_ws;
    float* A  = h + (size_t)BLTOK * 128;
    __hip_bfloat16* zy = (__hip_bfloat16*)(A + (size_t)BLTOK * 256);
    _Float16* ucb = (_Float16*)((char*)zy + (size_t)BLTOK * 256 * 2);
    _Float16* hb  = (_Float16*)((char*)ucb + (size_t)BLTOK * 256 * 2);
    float* E  = (float*)((char*)hb + (size_t)BLTOK * 128 * 2);
    _Float16* inwh  = (_Float16*)(E + (size_t)BLTOK * 128);
    _Float16* xpwh  = inwh + (size_t)12 * 512 * 128;
    _Float16* outwh = xpwh + (size_t)12 * 72 * 256;
    float* aggh = A + (size_t)BLTOK * 72;                 // 16*GCH*32*256 f32
    float* aggs = aggh + (size_t)16 * GCH * 32 * 256;     // 16*GCH*256 f32

    cvt_weights<<<(12 * 512 * 128 + 255) / 256, 256, 0, stream>>>(
        inw, inwh, xpw, xpwh, outw, outwh);
    pre_conv_gelu<<<BLTOK, 128, 0, stream>>>(x, pcw, pcb, h, hb);

    for (int blk = 0; blk < 6; ++blk) {
        for (int dir = 0; dir < 2; ++dir) {
            int s = blk * 2 + dir;
            // in_proj: hb @ in_w^T -> u fp32 (A) + z bf16 (zy).  N=512, K=128
            gemm_mfma<<<dim3(8, BLTOK / 64), 256, 0, stream>>>(
                hb, DMODEL, inwh + (size_t)s * 512 * 128, 128, A, zy,
                512, 128, dir, 1);
            // depthwise causal conv + silu: A -> ucb fp16
            dwconv_silu<<<16 * 128, 256, 0, stream>>>(
                A, cw + (size_t)s * 256 * 8, cb + (size_t)s * 256, ucb);
            // x_proj: ucb @ xp_w^T -> dbc (A, ldc=72).  N=72, K=256
            gemm_mfma<<<dim3(2, BLTOK / 64), 256, 0, stream>>>(
                ucb, DINNER, xpwh + (size_t)s * 72 * 256, 256, A, nullptr,
                72, 256, 0, 0);
            // chunked scan
            scan_phase1<<<16 * GCH, 256, 0, stream>>>(
                A, ucb, aggh, aggs,
                dtw + (size_t)s * 256 * 8, dtb + (size_t)s * 256,
                alog + (size_t)s * 256 * 32);
            scan_phase2<<<16 * 32, 256, 0, stream>>>(
                aggh, aggs, alog + (size_t)s * 256 * 32);
            scan_phase3<<<16 * GCH, 256, 0, stream>>>(
                A, ucb, zy, aggh,
                dtw + (size_t)s * 256 * 8, dtb + (size_t)s * 256,
                alog + (size_t)s * 256 * 32, dpar + (size_t)s * 256);
            // out_proj: y(fp16, in zy) @ out_w^T -> E.  N=128, K=256
            gemm_mfma<<<dim3(2, BLTOK / 64), 256, 0, stream>>>(
                (const _Float16*)zy, DINNER, outwh + (size_t)s * 128 * 256, 256, E, nullptr,
                128, 256, 0, 2 + dir);
        }
        combine_ln<<<BLTOK, 128, 0, stream>>>(
            E, h, hb, lng + blk * 128, lnb + blk * 128);
    }

    final_proj<<<BLTOK, 128, 0, stream>>>(h, pw, pb, out);
}

// Round 7
// 4558.296 us; speedup vs baseline: 15.2479x; 1.3642x over previous
//
#include <hip/hip_runtime.h>
#include <hip/hip_bf16.h>
#include <cstdint>
#include <cstddef>

// Problem constants
#define L_SEQ   4096
#define BATCH_N 16
#define BLTOK   (BATCH_N * L_SEQ)   // 65536 tokens
#define DMODEL  128
#define DINNER  256
#define DSTATE  32
#define DTRANK  8

// Scan chunking
#define LC  64                      // chunk length
#define GCH 64                      // chunks per sequence
#define LOG2E 1.44269504088896340736f

typedef _Float16 half8 __attribute__((ext_vector_type(8)));
typedef float    floatx4 __attribute__((ext_vector_type(4)));

#define LDSW 40   // LDS row stride in halves (32 data + 8 pad; 80B = 16B-aligned, 2-way banks = free)

// ---------------------------------------------------------------------------
// Pre-conv (1->128 channels, k=7, same padding) + exact GELU.  Writes fp32 + fp16.
// ---------------------------------------------------------------------------
__global__ __launch_bounds__(128) void pre_conv_gelu(
    const float* __restrict__ x,      // (16,4096,1)
    const float* __restrict__ w,      // (128,1,7)
    const float* __restrict__ bias,   // (128,)
    float* __restrict__ h,            // (BLTOK,128)
    _Float16* __restrict__ hb)        // (BLTOK,128)
{
    int r = blockIdx.x;
    int c = threadIdx.x;
    int b = r >> 12;
    int l = r & 4095;
    float acc = bias[c];
    const float* wp = w + c * 7;
#pragma unroll
    for (int k = 0; k < 7; ++k) {
        int ll = l + k - 3;
        if (ll >= 0 && ll < L_SEQ)
            acc += x[(size_t)(b << 12) + ll] * wp[k];
    }
    float ge = 0.5f * acc * (1.f + erff(acc * 0.70710678118654752f));
    h[(size_t)r * DMODEL + c]  = ge;
    hb[(size_t)r * DMODEL + c] = (_Float16)ge;
}

// ---------------------------------------------------------------------------
// Convert fp32 weights -> fp16 (runs once per launch; deterministic).
// ---------------------------------------------------------------------------
__global__ __launch_bounds__(256) void cvt_weights(
    const float* __restrict__ inw,  _Float16* __restrict__ inwh,   // 12*512*128
    const float* __restrict__ xpw,  _Float16* __restrict__ xpwh,   // 12*72*256
    const float* __restrict__ outw, _Float16* __restrict__ outwh)  // 12*128*256
{
    int i = blockIdx.x * 256 + threadIdx.x;
    if (i < 12 * 512 * 128) inwh[i]  = (_Float16)inw[i];
    if (i < 12 * 72 * 256)  xpwh[i]  = (_Float16)xpw[i];
    if (i < 12 * 128 * 256) outwh[i] = (_Float16)outw[i];
}

// ---------------------------------------------------------------------------
// MFMA fp16 GEMM: C[M,N] = A[M,K] @ W[N,K]^T, fp32 accumulate.
// 64x64 tile, 256 threads = 4 waves; wave w computes rows 16w..16w+15 x all
// 64 cols via 4 mfma_f32_16x16x32_f16.  K multiple of 32.
// rev!=0: A rows read per-batch flipped (L=4096).
// Epilogue modes:
//   0: x_proj  -> Out[row*72+col], col<N guarded
//   1: in_proj -> col<256: Out[row*256+col] (u fp32); col>=256: Zb bf16 (z)
//   2: out_proj fwd -> Out[row*128+col]
//   3: out_proj bwd -> Out[flip(row)*128+col] = 0.5*(existing + acc)
// ---------------------------------------------------------------------------
__global__ __launch_bounds__(256) void gemm_mfma(
    const _Float16* __restrict__ A, int lda,
    const _Float16* __restrict__ W, int ldw,   // N x ldw, K contiguous
    float* __restrict__ Out,
    __hip_bfloat16* __restrict__ Zb,
    int N, int K, int rev, int mode)
{
    __shared__ __align__(16) _Float16 As[64 * LDSW];
    __shared__ __align__(16) _Float16 Ws[64 * LDSW];

    int tid  = threadIdx.x;
    int wave = tid >> 6;
    int lane = tid & 63;
    int m0 = blockIdx.y * 64;
    int n0 = blockIdx.x * 64;

    // staging: thread t loads 16B of row (t>>2), k-chunk (t&3)*8
    int srow = tid >> 2;
    int skc  = (tid & 3) * 8;

    int garow = m0 + srow;
    if (rev) { int bb = garow >> 12; int ll = garow & 4095; garow = (bb << 12) + (4095 - ll); }
    const _Float16* Aptr = A + (size_t)garow * lda + skc;
    int wrow = n0 + srow;
    bool wok = (wrow < N);
    const _Float16* Wptr = W + (size_t)(wok ? wrow : 0) * ldw + skc;

    int lr = lane & 15;          // m (A) / n (B) / col (C)
    int lk = (lane >> 4) * 8;    // k offset within 32
    int soff = srow * LDSW + skc;
    int aoff = (16 * wave + lr) * LDSW + lk;

    floatx4 acc0 = {0.f, 0.f, 0.f, 0.f};
    floatx4 acc1 = acc0, acc2 = acc0, acc3 = acc0;

    for (int k0 = 0; k0 < K; k0 += 32) {
        half8 av = *(const half8*)(Aptr + k0);
        half8 bv = {};
        if (wok) bv = *(const half8*)(Wptr + k0);
        __syncthreads();
        *(half8*)&As[soff] = av;
        *(half8*)&Ws[soff] = bv;
        __syncthreads();
        half8 af = *(const half8*)&As[aoff];
        half8 b0 = *(const half8*)&Ws[( 0 + lr) * LDSW + lk];
        half8 b1 = *(const half8*)&Ws[(16 + lr) * LDSW + lk];
        half8 b2 = *(const half8*)&Ws[(32 + lr) * LDSW + lk];
        half8 b3 = *(const half8*)&Ws[(48 + lr) * LDSW + lk];
        acc0 = __builtin_amdgcn_mfma_f32_16x16x32_f16(af, b0, acc0, 0, 0, 0);
        acc1 = __builtin_amdgcn_mfma_f32_16x16x32_f16(af, b1, acc1, 0, 0, 0);
        acc2 = __builtin_amdgcn_mfma_f32_16x16x32_f16(af, b2, acc2, 0, 0, 0);
        acc3 = __builtin_amdgcn_mfma_f32_16x16x32_f16(af, b3, acc3, 0, 0, 0);
    }

    // C/D layout: col = lane&15, row = (lane>>4)*4 + reg
    int orow = m0 + 16 * wave + (lane >> 4) * 4;
    floatx4 av4[4] = {acc0, acc1, acc2, acc3};
#pragma unroll
    for (int jb = 0; jb < 4; ++jb) {
        int col = n0 + jb * 16 + lr;
#pragma unroll
        for (int r = 0; r < 4; ++r) {
            int row = orow + r;
            float v = av4[jb][r];
            if (mode == 0) {
                if (col < N) Out[(size_t)row * 72 + col] = v;
            } else if (mode == 1) {
                if (col < 256) Out[(size_t)row * 256 + col] = v;
                else Zb[(size_t)row * 256 + (col - 256)] = __float2bfloat16(v);
            } else if (mode == 2) {
                Out[(size_t)row * 128 + col] = v;
            } else {
                int bb = row >> 12, ll = row & 4095;
                size_t o = ((size_t)(bb << 12) + (4095 - ll)) * 128 + col;
                Out[o] = 0.5f * (Out[o] + v);
            }
        }
    }
}

// ---------------------------------------------------------------------------
// Depthwise causal conv (k=8, pad (7,0)) + SiLU, register sliding window.
// Reads u fp32 (stride 256), writes uc fp16.
// ---------------------------------------------------------------------------
__global__ __launch_bounds__(256) void dwconv_silu(
    const float* __restrict__ u,      // (BLTOK,256)
    const float* __restrict__ cw,     // (256,1,8)
    const float* __restrict__ cb,     // (256,)
    _Float16* __restrict__ uc)        // (BLTOK,256)
{
    int b  = blockIdx.x >> 7;
    int lt = blockIdx.x & 127;
    int l0 = lt * 32;
    int d  = threadIdx.x;

    float wv[8];
    const float* wp = cw + d * 8;
#pragma unroll
    for (int k = 0; k < 8; ++k) wv[k] = wp[k];
    float bias = cb[d];

    size_t rowb = (size_t)(b << 12);
    float win[8];
#pragma unroll
    for (int j = 0; j < 7; ++j) {
        int ll = l0 - 7 + j;
        win[j] = (ll >= 0) ? u[(rowb + ll) * DINNER + d] : 0.f;
    }
#pragma unroll
    for (int i = 0; i < 32; ++i) {
        int l = l0 + i;
        win[7] = u[(rowb + l) * DINNER + d];
        float acc = bias;
#pragma unroll
        for (int j = 0; j < 8; ++j) acc += win[j] * wv[j];
        float s = acc / (1.f + __expf(-acc));
        uc[(rowb + l) * DINNER + d] = (_Float16)s;
#pragma unroll
        for (int j = 0; j < 7; ++j) win[j] = win[j + 1];
    }
}

// ---------------------------------------------------------------------------
// Chunked selective scan, lane = channel d, h[32] states in registers.
// Phase 1: zero-init local scan -> h_end[32], S = sum(dt).
// __launch_bounds__(256,4): grid is 1024 blocks = 4 blocks/CU, so allow
// 128 VGPRs (h[32]+al2[32]+temps) — at (256) default the compiler capped
// at 56 VGPRs and spilled al2 to scratch (measured R6: 241us, VGPR=56).
// ---------------------------------------------------------------------------
__global__ __launch_bounds__(256, 4) void scan_phase1(
    const float* __restrict__ dbc,    // (BLTOK,72)
    const _Float16* __restrict__ u,   // (BLTOK,256)
    float* __restrict__ aggh,
    float* __restrict__ aggs,
    const float* __restrict__ dt_w,
    const float* __restrict__ dt_b,
    const float* __restrict__ a_log)
{
    __shared__ __align__(16) float sh[LC * 72];
    int bg = blockIdx.x;
    int b  = bg >> 6;
    int g  = bg & (GCH - 1);
    int d  = threadIdx.x;

    size_t base = (size_t)b * L_SEQ + (size_t)g * LC;
    const float* src = dbc + base * 72;
    for (int i = d; i < LC * 72; i += 256) sh[i] = src[i];

    const float* wr = dt_w + d * DTRANK;
    float w0 = wr[0], w1 = wr[1], w2 = wr[2], w3 = wr[3];
    float w4 = wr[4], w5 = wr[5], w6 = wr[6], w7 = wr[7];
    float bias = dt_b[d];

    float al2[32];
    {
        const float4* ar = (const float4*)(a_log + d * DSTATE);
#pragma unroll
        for (int k = 0; k < 8; ++k) {
            float4 v = ar[k];
            al2[4 * k + 0] = -__expf(v.x) * LOG2E;
            al2[4 * k + 1] = -__expf(v.y) * LOG2E;
            al2[4 * k + 2] = -__expf(v.z) * LOG2E;
            al2[4 * k + 3] = -__expf(v.w) * LOG2E;
        }
    }
    __syncthreads();

    float h[32];
#pragma unroll
    for (int n = 0; n < 32; ++n) h[n] = 0.f;
    float S = 0.f;

    for (int t = 0; t < LC; ++t) {
        const float* row = sh + t * 72;
        float4 r0 = *(const float4*)row;
        float4 r1 = *(const float4*)(row + 4);
        float dtr = bias + r0.x * w0 + r0.y * w1 + r0.z * w2 + r0.w * w3
                         + r1.x * w4 + r1.y * w5 + r1.z * w6 + r1.w * w7;
        float dtv = (dtr > 15.f) ? dtr : __logf(1.f + __expf(dtr));
        S += dtv;
        float du = dtv * (float)u[(base + t) * DINNER + d];
#pragma unroll
        for (int n = 0; n < 32; n += 4) {
            float4 Bv = *(const float4*)(row + 8 + n);
            h[n + 0] = h[n + 0] * __builtin_amdgcn_exp2f(dtv * al2[n + 0]) + du * Bv.x;
            h[n + 1] = h[n + 1] * __builtin_amdgcn_exp2f(dtv * al2[n + 1]) + du * Bv.y;
            h[n + 2] = h[n + 2] * __builtin_amdgcn_exp2f(dtv * al2[n + 2]) + du * Bv.z;
            h[n + 3] = h[n + 3] * __builtin_amdgcn_exp2f(dtv * al2[n + 3]) + du * Bv.w;
        }
    }

    size_t ob = ((size_t)(b * GCH + g) * 32) * 256 + d;
#pragma unroll
    for (int n = 0; n < 32; ++n) aggh[ob + (size_t)n * 256] = h[n];
    aggs[(size_t)(b * GCH + g) * 256 + d] = S;
}

// ---------------------------------------------------------------------------
// Phase 2: serial combine across chunks.  P_n = exp(a_n * S_g).
// ---------------------------------------------------------------------------
__global__ __launch_bounds__(256) void scan_phase2(
    float* __restrict__ aggh,
    const float* __restrict__ aggs,
    const float* __restrict__ a_log)
{
    int b = blockIdx.x >> 5;
    int n = blockIdx.x & 31;
    int d = threadIdx.x;

    float a = -__expf(a_log[d * DSTATE + n]);
    float hrun = 0.f;
    for (int g = 0; g < GCH; ++g) {
        size_t os = (size_t)(b * GCH + g) * 256 + d;
        size_t oh = ((size_t)(b * GCH + g) * 32 + n) * 256 + d;
        float S  = aggs[os];
        float he = aggh[oh];
        aggh[oh] = hrun;
        hrun = hrun * __expf(a * S) + he;
    }
}

// ---------------------------------------------------------------------------
// Phase 3: local scan seeded with h_in; fused y = <h,C>, D skip, silu(z).
// Reads z (bf16) and writes y (fp16) to the SAME buffer slot (thread-local
// read-before-write).  __launch_bounds__(256,4): see scan_phase1 note.
// ---------------------------------------------------------------------------
__global__ __launch_bounds__(256, 4) void scan_phase3(
    const float* __restrict__ dbc,     // (BLTOK,72)
    const _Float16* __restrict__ u,    // (BLTOK,256)
    __hip_bfloat16* __restrict__ zy,   // (BLTOK,256): z bf16 in, y fp16 out
    const float* __restrict__ aggh,
    const float* __restrict__ dt_w,
    const float* __restrict__ dt_b,
    const float* __restrict__ a_log,
    const float* __restrict__ Dp)
{
    __shared__ __align__(16) float sh[LC * 72];
    int bg = blockIdx.x;
    int b  = bg >> 6;
    int g  = bg & (GCH - 1);
    int d  = threadIdx.x;

    size_t base = (size_t)b * L_SEQ + (size_t)g * LC;
    const float* src = dbc + base * 72;
    for (int i = d; i < LC * 72; i += 256) sh[i] = src[i];

    const float* wr = dt_w + d * DTRANK;
    float w0 = wr[0], w1 = wr[1], w2 = wr[2], w3 = wr[3];
    float w4 = wr[4], w5 = wr[5], w6 = wr[6], w7 = wr[7];
    float bias = dt_b[d];
    float Dd = Dp[d];

    float al2[32];
    {
        const float4* ar = (const float4*)(a_log + d * DSTATE);
#pragma unroll
        for (int k = 0; k < 8; ++k) {
            float4 v = ar[k];
            al2[4 * k + 0] = -__expf(v.x) * LOG2E;
            al2[4 * k + 1] = -__expf(v.y) * LOG2E;
            al2[4 * k + 2] = -__expf(v.z) * LOG2E;
            al2[4 * k + 3] = -__expf(v.w) * LOG2E;
        }
    }

    float h[32];
    size_t ob = ((size_t)(b * GCH + g) * 32) * 256 + d;
#pragma unroll
    for (int n = 0; n < 32; ++n) h[n] = aggh[ob + (size_t)n * 256];

    __syncthreads();

    _Float16* yo = (_Float16*)zy;

    for (int t = 0; t < LC; ++t) {
        const float* row = sh + t * 72;
        float4 r0 = *(const float4*)row;
        float4 r1 = *(const float4*)(row + 4);
        float dtr = bias + r0.x * w0 + r0.y * w1 + r0.z * w2 + r0.w * w3
                         + r1.x * w4 + r1.y * w5 + r1.z * w6 + r1.w * w7;
        float dtv = (dtr > 15.f) ? dtr : __logf(1.f + __expf(dtr));
        float uv = (float)u[(base + t) * DINNER + d];
        float du = dtv * uv;
        float zv = __bfloat162float(zy[(base + t) * DINNER + d]);

        float y = 0.f;
#pragma unroll
        for (int n = 0; n < 32; n += 4) {
            float4 Bv = *(const float4*)(row + 8 + n);
            float4 Cv = *(const float4*)(row + 40 + n);
            h[n + 0] = h[n + 0] * __builtin_amdgcn_exp2f(dtv * al2[n + 0]) + du * Bv.x;
            h[n + 1] = h[n + 1] * __builtin_amdgcn_exp2f(dtv * al2[n + 1]) + du * Bv.y;
            h[n + 2] = h[n + 2] * __builtin_amdgcn_exp2f(dtv * al2[n + 2]) + du * Bv.z;
            h[n + 3] = h[n + 3] * __builtin_amdgcn_exp2f(dtv * al2[n + 3]) + du * Bv.w;
            y += h[n + 0] * Cv.x + h[n + 1] * Cv.y
               + h[n + 2] * Cv.z + h[n + 3] * Cv.w;
        }
        float yv = y + uv * Dd;
        float sig = 1.f / (1.f + __expf(-zv));
        yo[(base + t) * DINNER + d] = (_Float16)(yv * (zv * sig));
    }
}

// ---------------------------------------------------------------------------
// h = LayerNorm(osum + h); writes fp32 h and fp16 hb
// ---------------------------------------------------------------------------
__global__ __launch_bounds__(128) void combine_ln(
    const float* __restrict__ osum,   // (BLTOK,128)
    float* __restrict__ h,            // (BLTOK,128)
    _Float16* __restrict__ hb,        // (BLTOK,128)
    const float* __restrict__ g,
    const float* __restrict__ be)
{
    __shared__ float red[128];
    int r = blockIdx.x;
    int c = threadIdx.x;
    size_t idx = (size_t)r * DMODEL + c;

    float v = osum[idx] + h[idx];

    red[c] = v;
    __syncthreads();
    for (int s = 64; s > 0; s >>= 1) {
        if (c < s) red[c] += red[c + s];
        __syncthreads();
    }
    float mu = red[0] * (1.f / 128.f);
    __syncthreads();
    float dv = v - mu;
    red[c] = dv * dv;
    __syncthreads();
    for (int s = 64; s > 0; s >>= 1) {
        if (c < s) red[c] += red[c + s];
        __syncthreads();
    }
    float var = red[0] * (1.f / 128.f);
    float o = dv * rsqrtf(var + 1e-5f) * g[c] + be[c];
    h[idx]  = o;
    hb[idx] = (_Float16)o;
}

// ---------------------------------------------------------------------------
__global__ __launch_bounds__(128) void final_proj(
    const float* __restrict__ h,
    const float* __restrict__ pw,     // (1,128)
    const float* __restrict__ pb,     // (1,)
    float* __restrict__ out)          // (BLTOK,)
{
    __shared__ float red[128];
    int r = blockIdx.x;
    int c = threadIdx.x;
    red[c] = h[(size_t)r * DMODEL + c] * pw[c];
    __syncthreads();
    for (int s = 64; s > 0; s >>= 1) {
        if (c < s) red[c] += red[c + s];
        __syncthreads();
    }
    if (c == 0) out[r] = red[0] + pb[0];
}

// ---------------------------------------------------------------------------
extern "C" void kernel_launch(void* const* d_in, const int* in_sizes, int n_in,
                              void* d_out, int out_size, void* d_ws, size_t ws_size,
                              hipStream_t stream)
{
    const float* x    = (const float*)d_in[0];
    const float* pcw  = (const float*)d_in[1];
    const float* pcb  = (const float*)d_in[2];
    const float* inw  = (const float*)d_in[3];
    const float* cw   = (const float*)d_in[4];
    const float* cb   = (const float*)d_in[5];
    const float* xpw  = (const float*)d_in[6];
    const float* dtw  = (const float*)d_in[7];
    const float* dtb  = (const float*)d_in[8];
    const float* alog = (const float*)d_in[9];
    const float* dpar = (const float*)d_in[10];
    const float* outw = (const float*)d_in[11];
    const float* lng  = (const float*)d_in[12];
    const float* lnb  = (const float*)d_in[13];
    const float* pw   = (const float*)d_in[14];
    const float* pb   = (const float*)d_in[15];
    float* out = (float*)d_out;

    // Workspace layout (~211 MiB, lifetime-aliased):
    //   h    : BLTOK*128 f32   residual stream
    //   A    : BLTOK*256 f32   u fp32 (in_proj) -> dbc (72 cols) + agg tail
    //   zy   : BLTOK*256 2B    z bf16 (in_proj) -> y fp16 (scan, in-place)
    //   ucb  : BLTOK*256 f16   conv output (scan input)
    //   hb   : BLTOK*128 f16   fp16 shadow of h (GEMM input)
    //   E    : BLTOK*128 f32   0.5*(fwd + flip(bwd)) accumulation
    //   w16  : fp16 weights (inwh | xpwh | outwh)
    float* h  = (float*)d_ws;
    float* A  = h + (size_t)BLTOK * 128;
    __hip_bfloat16* zy = (__hip_bfloat16*)(A + (size_t)BLTOK * 256);
    _Float16* ucb = (_Float16*)((char*)zy + (size_t)BLTOK * 256 * 2);
    _Float16* hb  = (_Float16*)((char*)ucb + (size_t)BLTOK * 256 * 2);
    float* E  = (float*)((char*)hb + (size_t)BLTOK * 128 * 2);
    _Float16* inwh  = (_Float16*)(E + (size_t)BLTOK * 128);
    _Float16* xpwh  = inwh + (size_t)12 * 512 * 128;
    _Float16* outwh = xpwh + (size_t)12 * 72 * 256;
    float* aggh = A + (size_t)BLTOK * 72;                 // 16*GCH*32*256 f32
    float* aggs = aggh + (size_t)16 * GCH * 32 * 256;     // 16*GCH*256 f32

    cvt_weights<<<(12 * 512 * 128 + 255) / 256, 256, 0, stream>>>(
        inw, inwh, xpw, xpwh, outw, outwh);
    pre_conv_gelu<<<BLTOK, 128, 0, stream>>>(x, pcw, pcb, h, hb);

    for (int blk = 0; blk < 6; ++blk) {
        for (int dir = 0; dir < 2; ++dir) {
            int s = blk * 2 + dir;
            // in_proj: hb @ in_w^T -> u fp32 (A) + z bf16 (zy).  N=512, K=128
            gemm_mfma<<<dim3(8, BLTOK / 64), 256, 0, stream>>>(
                hb, DMODEL, inwh + (size_t)s * 512 * 128, 128, A, zy,
                512, 128, dir, 1);
            // depthwise causal conv + silu: A -> ucb fp16
            dwconv_silu<<<16 * 128, 256, 0, stream>>>(
                A, cw + (size_t)s * 256 * 8, cb + (size_t)s * 256, ucb);
            // x_proj: ucb @ xp_w^T -> dbc (A, ldc=72).  N=72, K=256
            gemm_mfma<<<dim3(2, BLTOK / 64), 256, 0, stream>>>(
                ucb, DINNER, xpwh + (size_t)s * 72 * 256, 256, A, nullptr,
                72, 256, 0, 0);
            // chunked scan
            scan_phase1<<<16 * GCH, 256, 0, stream>>>(
                A, ucb, aggh, aggs,
                dtw + (size_t)s * 256 * 8, dtb + (size_t)s * 256,
                alog + (size_t)s * 256 * 32);
            scan_phase2<<<16 * 32, 256, 0, stream>>>(
                aggh, aggs, alog + (size_t)s * 256 * 32);
            scan_phase3<<<16 * GCH, 256, 0, stream>>>(
                A, ucb, zy, aggh,
                dtw + (size_t)s * 256 * 8, dtb + (size_t)s * 256,
                alog + (size_t)s * 256 * 32, dpar + (size_t)s * 256);
            // out_proj: y(fp16, in zy) @ out_w^T -> E.  N=128, K=256
            gemm_mfma<<<dim3(2, BLTOK / 64), 256, 0, stream>>>(
                (const _Float16*)zy, DINNER, outwh + (size_t)s * 128 * 256, 256, E, nullptr,
                128, 256, 0, 2 + dir);
        }
        combine_ln<<<BLTOK, 128, 0, stream>>>(
            E, h, hb, lng + blk * 128, lnb + blk * 128);
    }

    final_proj<<<BLTOK, 128, 0, stream>>>(h, pw, pb, out);
}